// Round 10
// baseline (182.354 us; speedup 1.0000x reference)
//
#include <hip/hip_runtime.h>
#include <math.h>

#define Bsz 8
#define Cch 512
#define Npx 1024
#define TOPK 12
#define BN (Bsz * Npx)

typedef __attribute__((ext_vector_type(8))) short bf16x8;
typedef __attribute__((ext_vector_type(4))) float f32x4;

__device__ __forceinline__ unsigned short f2bf(float x) {
    unsigned u = __float_as_uint(x);
    u += 0x7FFF + ((u >> 16) & 1);
    return (unsigned short)(u >> 16);
}
__device__ __forceinline__ float bf2f(unsigned short h) {
    return __uint_as_float(((unsigned)h) << 16);
}

// ---------------- reduction helpers ----------------
__device__ __forceinline__ float warp_sum64(float v) {
    for (int o = 32; o > 0; o >>= 1) v += __shfl_down(v, o);
    return v;
}
__device__ __forceinline__ float block_sum512(float v, float* s8) {
    v = warp_sum64(v);
    int lane = threadIdx.x & 63, w = threadIdx.x >> 6;
    __syncthreads();
    if (lane == 0) s8[w] = v;
    __syncthreads();
    float r = 0.f;
    #pragma unroll
    for (int k = 0; k < 8; k++) r += s8[k];
    return r;
}

// ---------------- 1: masked average pool (float4, single-barrier) -------------
// grid (Cch, Bsz), block 256
__global__ void k_pool(const float* __restrict__ sf, const int* __restrict__ mask,
                       float* __restrict__ FPo, float* __restrict__ BPo) {
    __shared__ float s4a[4], s4b[4], s4c[4];
    int c = blockIdx.x, b = blockIdx.y, t = threadIdx.x;
    const float4* f4 = (const float4*)(sf + ((size_t)b * Cch + c) * Npx);
    const int4* m4 = (const int4*)(mask + (size_t)b * Npx);
    float4 v = f4[t];
    int4 m = m4[t];
    float sumf = (m.x == 1 ? v.x : 0.f) + (m.y == 1 ? v.y : 0.f)
               + (m.z == 1 ? v.z : 0.f) + (m.w == 1 ? v.w : 0.f);
    float tot = v.x + v.y + v.z + v.w;
    float cf = (float)((m.x == 1) + (m.y == 1) + (m.z == 1) + (m.w == 1));
    sumf = warp_sum64(sumf);
    tot  = warp_sum64(tot);
    cf   = warp_sum64(cf);
    int lane = t & 63, w = t >> 6;
    if (lane == 0) { s4a[w] = sumf; s4b[w] = tot; s4c[w] = cf; }
    __syncthreads();
    if (t == 0) {
        float sA = s4a[0] + s4a[1] + s4a[2] + s4a[3];
        float sB = s4b[0] + s4b[1] + s4b[2] + s4b[3];
        float sC = s4c[0] + s4c[1] + s4c[2] + s4c[3];
        FPo[b * Cch + c] = sA / (sC + 1e-5f);
        BPo[b * Cch + c] = (sB - sA) / ((1024.f - sC) + 1e-5f);
    }
}

// ---------------- 2: pred logit + bf16 cast (block 512: 16 thr/pixel) ---------
// grid (Npx/32, Bsz), block 512.
__global__ void __launch_bounds__(512) k_predcast(const float* __restrict__ fq,
                       const float* __restrict__ FP, const float* __restrict__ BP,
                       float* __restrict__ dsim, float* __restrict__ invn,
                       unsigned short* __restrict__ Ft) {
    __shared__ float sFP[Cch], sBP[Cch], s8[8];
    __shared__ float rdf[16][32], rdb[16][32], rqq[16][32];
    __shared__ unsigned short S[32][522];   // odd dword stride -> conflict-free
    int b = blockIdx.y, t = threadIdx.x;
    int tx = t & 31, ty = t >> 5;           // ty in [0,16)
    int p0 = blockIdx.x * 32;
    int p = p0 + tx;
    sFP[t] = FP[b * Cch + t];
    sBP[t] = BP[b * Cch + t];
    __syncthreads();
    float nf = sqrtf(block_sum512(sFP[t] * sFP[t], s8));
    float nb = sqrtf(block_sum512(sBP[t] * sBP[t], s8));
    const float* q = fq + (size_t)b * Cch * Npx + p;
    float df = 0.f, db = 0.f, qq = 0.f;
    int c0 = ty * 32;
    #pragma unroll 4
    for (int c = 0; c < 32; c += 2) {
        float v0 = q[(size_t)(c0 + c) * Npx];
        float v1 = q[(size_t)(c0 + c + 1) * Npx];
        df += v0 * sFP[c0 + c] + v1 * sFP[c0 + c + 1];
        db += v0 * sBP[c0 + c] + v1 * sBP[c0 + c + 1];
        qq += v0 * v0 + v1 * v1;
        unsigned pk = (unsigned)f2bf(v0) | ((unsigned)f2bf(v1) << 16);
        *(unsigned*)&S[tx][c0 + c] = pk;
    }
    rdf[ty][tx] = df; rdb[ty][tx] = db; rqq[ty][tx] = qq;
    __syncthreads();
    for (int s = 8; s > 0; s >>= 1) {
        if (ty < s) {
            rdf[ty][tx] += rdf[ty + s][tx];
            rdb[ty][tx] += rdb[ty + s][tx];
            rqq[ty][tx] += rqq[ty + s][tx];
        }
        __syncthreads();
    }
    if (ty == 0) {
        float nq = sqrtf(rqq[0][tx]);
        float simf = 10.f * rdf[0][tx] / fmaxf(nq * nf, 1e-8f);
        float simb = 10.f * rdb[0][tx] / fmaxf(nq * nb, 1e-8f);
        dsim[b * Npx + p] = simf - simb;
        invn[b * Npx + p] = 1.f / nq;
    }
    // write Ft rows (coalesced dword stores, conflict-free LDS dword reads)
    int w = t >> 6, lane = t & 63;           // 8 waves
    unsigned short* FtB = Ft + (size_t)b * Npx * Cch;
    for (int pr = w; pr < 32; pr += 8) {
        unsigned* dst = (unsigned*)(FtB + (size_t)(p0 + pr) * Cch);
        #pragma unroll
        for (int it = 0; it < 4; it++) {
            int d = it * 64 + lane;
            dst[d] = *(const unsigned*)&S[pr][d * 2];
        }
    }
}

// ---------------- 3: select + compact + prototypes + FP1/nf + wiv -------------
// grid (2, Bsz), block 1024 (16 waves). x=0: fg, x=1: bg
// Emits wiv[b][j] = (bg-selected ? invn[j] : 0) for the fused masked attention.
__global__ void __launch_bounds__(1024) k_selcompact(const float* __restrict__ dsim,
                        const float* __restrict__ invn,
                        const unsigned short* __restrict__ Ft,
                        const float* __restrict__ FP,
                        int* __restrict__ nsf, int* __restrict__ nsb,
                        int* __restrict__ jf, int* __restrict__ jb,
                        float* __restrict__ wiv,
                        float* __restrict__ fgp, float* __restrict__ bgp,
                        float* __restrict__ FP1, float* __restrict__ nfv) {
    __shared__ int wsum[16];
    __shared__ int sns;
    __shared__ float sProto[16][512];       // 32 KB
    __shared__ float s16f[16];
    int b = blockIdx.y, t = threadIdx.x;
    int lane = t & 63, w = t >> 6;
    bool isf = (blockIdx.x == 0);
    float d = dsim[b * Npx + t];
    float key = isf ? d : -d;
    float thres = isf ? 0.8472979f : 0.4054651f;   // ln(0.7/0.3), ln(0.6/0.4)
    int flag = (key > thres) ? 1 : 0;
    int x = flag;
    #pragma unroll
    for (int o = 1; o < 64; o <<= 1) {
        int y = __shfl_up(x, o);
        if (lane >= o) x += y;
    }
    if (lane == 63) wsum[w] = x;
    __syncthreads();
    int base = 0, total = 0;
    #pragma unroll
    for (int k = 0; k < 16; k++) {
        int s = wsum[k];
        if (k < w) base += s;
        total += s;
    }
    int* jdst = (isf ? jf : jb) + b * Npx;
    if (total == 0) {
        // cold path: top-12 fallback (lower index wins ties)
        __shared__ int   sc[Npx];
        __shared__ float v[Npx];
        __shared__ float rv[Npx];
        __shared__ int   ri[Npx];
        v[t] = key; flag = 0;
        __syncthreads();
        for (int k = 0; k < TOPK; k++) {
            rv[t] = v[t]; ri[t] = t;
            __syncthreads();
            for (int s = 512; s > 0; s >>= 1) {
                if (t < s) {
                    float a = rv[t], bb = rv[t + s];
                    int ia = ri[t], ib = ri[t + s];
                    if (bb > a || (bb == a && ib < ia)) { rv[t] = bb; ri[t] = ib; }
                }
                __syncthreads();
            }
            int win = ri[0];
            if (t == win) { flag = 1; v[t] = -INFINITY; }
            __syncthreads();
        }
        sc[t] = flag;
        __syncthreads();
        for (int off = 1; off < 1024; off <<= 1) {
            int xx = (t >= off) ? sc[t - off] : 0;
            __syncthreads();
            sc[t] += xx;
            __syncthreads();
        }
        if (flag) jdst[sc[t] - 1] = t;
        if (t == 1023) sns = sc[1023];
    } else {
        if (flag) jdst[base + x - 1] = t;
        if (t == 0) sns = total;
    }
    if (!isf) wiv[b * Npx + t] = flag ? invn[b * Npx + t] : 0.f;
    __syncthreads();                         // jdst writes + sns visible to block
    int ns = sns;
    if (t == 0) (isf ? nsf : nsb)[b] = ns;
    // ---- prototype: mean of selected Ft rows (coalesced 1KB row reads) ----
    const unsigned short* FtB = Ft + (size_t)b * Npx * Cch;
    float facc[8] = {0.f, 0.f, 0.f, 0.f, 0.f, 0.f, 0.f, 0.f};
    int k = w;
    int row = (k < ns) ? jdst[k] : 0;
    while (k < ns) {
        int kn = k + 16;
        int rown = (kn < ns) ? jdst[kn] : 0;   // prefetch index
        bf16x8 vv = *(const bf16x8*)&FtB[(size_t)row * Cch + lane * 8];
        #pragma unroll
        for (int e = 0; e < 8; e++) facc[e] += bf2f((unsigned short)vv[e]);
        k = kn; row = rown;
    }
    #pragma unroll
    for (int e = 0; e < 8; e++) sProto[w][lane * 8 + e] = facc[e];
    __syncthreads();
    float fp1 = 0.f;
    if (t < 512) {
        float s = 0.f;
        #pragma unroll
        for (int q = 0; q < 16; q++) s += sProto[q][t];
        float pv = s / (float)ns;
        (isf ? fgp : bgp)[b * Cch + t] = pv;
        if (isf) {
            fp1 = 0.5f * FP[b * Cch + t] + 0.5f * pv;
            FP1[b * Cch + t] = fp1;
        }
    }
    if (isf) {
        // ||FP1|| for the final fg similarity
        float v2 = warp_sum64(fp1 * fp1);
        if (lane == 0) s16f[w] = v2;
        __syncthreads();
        if (t == 0) {
            float nn = 0.f;
            #pragma unroll
            for (int q = 0; q < 16; q++) nn += s16f[q];
            nfv[b] = sqrtf(nn);
        }
    }
}

// ---------------- 4: FUSED masked attention + PV + finalize (full-j) ----------
// grid (32, Bsz) = 256 blocks, block 512 (8 waves), ~136 KB LDS.
// Full-j formulation: P[i][j] = wiv[j]>0 ? exp(sim*2*invn_i*invn_j) : 0 over ALL
// 1024 j -- B/V operands are LINEAR Ft rows (no index gather chains).
__global__ void __launch_bounds__(512) k_fused(
        const unsigned short* __restrict__ Ft,
        const float* __restrict__ wiv, const float* __restrict__ invn,
        const float* __restrict__ bgp, const float* __restrict__ FP1,
        const float* __restrict__ nfv, float* __restrict__ out) {
    __shared__ unsigned short Afull[32][520];   // q rows, full K (33.3 KB)
    __shared__ unsigned short sP[32][1032];     // attention rows (66 KB)
    __shared__ unsigned short Buf[128 * 136];   // ph1 Bt[128][136] / ph2 Vt[64][264] (34.8 KB)
    __shared__ float sWiv[Npx];                 // masked invn (4 KB)
    __shared__ float sfi[32], sden[32];
    __shared__ float sfp1c[64], sbgc[64];
    __shared__ float spart[32][4];

    int b = blockIdx.y;
    int i0 = blockIdx.x * 32;
    int tid = threadIdx.x;
    int l = tid & 63, w = tid >> 6;
    int ml = l & 15, quad = l >> 4;
    const unsigned short* FtB = Ft + (size_t)b * Npx * Cch;

    // ---- stage A (q rows, full K) + tables ----
    #pragma unroll
    for (int s = 0; s < 4; s++) {
        int idx = tid + s * 512;
        int row = idx >> 6, kc8 = (idx & 63) * 8;
        *(uint4*)&Afull[row][kc8] = *(const uint4*)(FtB + (size_t)(i0 + row) * Cch + kc8);
    }
    #pragma unroll
    for (int s = 0; s < 2; s++) sWiv[tid + s * 512] = wiv[b * Npx + tid + s * 512];
    if (tid < 32) sfi[tid] = 2.f * invn[b * Npx + i0 + tid];

    // ---- phase 1: gram rows (linear B) -> sP = exp(sim)*mask (bf16) ----
    // 8 waves tile 32i x 128j; per wave 16i x 32j. k-step 128.
    int ig = w & 1, jg = w >> 1;            // jg in [0,4)
    int brow = tid >> 2, bk = (tid & 3) * 32;   // staging: 4 thr/row, 32 ush each
    for (int j0 = 0; j0 < Npx; j0 += 128) {
        const unsigned short* src = FtB + (size_t)(j0 + brow) * Cch + bk;
        uint4 v0 = *(const uint4*)src;
        uint4 v1 = *(const uint4*)(src + 8);
        uint4 v2 = *(const uint4*)(src + 16);
        uint4 v3 = *(const uint4*)(src + 24);
        f32x4 acc0 = {}, acc1 = {};
        for (int k0 = 0; k0 < Cch; k0 += 128) {
            __syncthreads();
            unsigned short* bd = &Buf[brow * 136 + bk];
            *(uint4*)bd = v0;        *(uint4*)(bd + 8) = v1;
            *(uint4*)(bd + 16) = v2; *(uint4*)(bd + 24) = v3;
            __syncthreads();
            int kn = k0 + 128;
            if (kn < Cch) {
                v0 = *(const uint4*)(src + kn);      v1 = *(const uint4*)(src + kn + 8);
                v2 = *(const uint4*)(src + kn + 16); v3 = *(const uint4*)(src + kn + 24);
            }
            #pragma unroll
            for (int h = 0; h < 4; h++) {
                bf16x8 af = *(const bf16x8*)&Afull[ig * 16 + ml][k0 + h * 32 + quad * 8];
                bf16x8 bf0 = *(const bf16x8*)&Buf[(jg * 32 + ml) * 136 + h * 32 + quad * 8];
                bf16x8 bf1 = *(const bf16x8*)&Buf[(jg * 32 + 16 + ml) * 136 + h * 32 + quad * 8];
                acc0 = __builtin_amdgcn_mfma_f32_16x16x32_bf16(af, bf0, acc0, 0, 0, 0);
                acc1 = __builtin_amdgcn_mfma_f32_16x16x32_bf16(af, bf1, acc1, 0, 0, 0);
            }
        }
        #pragma unroll
        for (int r = 0; r < 4; r++) {
            int il = ig * 16 + quad * 4 + r;
            float fi = sfi[il];
            int jl0 = j0 + jg * 32 + ml;
            float w0 = sWiv[jl0], w1 = sWiv[jl0 + 16];
            sP[il][jl0]      = f2bf(w0 > 0.f ? __expf(acc0[r] * fi * w0) : 0.f);
            sP[il][jl0 + 16] = f2bf(w1 > 0.f ? __expf(acc1[r] * fi * w1) : 0.f);
        }
    }
    __syncthreads();

    // ---- row denominators + zero partials ----
    {
        int i = tid >> 4, jj16 = tid & 15;
        float s = 0.f;
        for (int j = jj16; j < Npx; j += 16) s += bf2f(sP[i][j]);
        #pragma unroll
        for (int m = 1; m < 16; m <<= 1) s += __shfl_xor(s, m);
        if (jj16 == 0) sden[i] = s;
    }
    if (tid < 128) ((float*)spart)[tid] = 0.f;
    __syncthreads();

    // ---- phase 2: PV over all c (linear V, in-LDS transpose) + partials ----
    int cgw = w & 3, igw = w >> 2;
    int icol = igw * 16 + ml;
    float rdi = 1.f / sden[icol];
    float sdb = 0.f, snb = 0.f, sdf = 0.f, sqq = 0.f;
    int jr = tid >> 1, ch0 = (tid & 1) * 32;    // staging: 2 thr/row, 32 c each
    for (int c0 = 0; c0 < Cch; c0 += 64) {
        __syncthreads();                        // sfp1c/sbgc safe to overwrite
        if (tid < 64) {
            sfp1c[tid] = FP1[b * Cch + c0 + tid];
            sbgc[tid]  = 0.3f * bgp[b * Cch + c0 + tid];
        }
        f32x4 accp = {};
        const unsigned short* vsrc = FtB + (size_t)jr * Cch + c0 + ch0;
        uint4 u0 = *(const uint4*)vsrc;
        uint4 u1 = *(const uint4*)(vsrc + 8);
        uint4 u2 = *(const uint4*)(vsrc + 16);
        uint4 u3 = *(const uint4*)(vsrc + 24);
        for (int j0 = 0; j0 < Npx; j0 += 256) {
            __syncthreads();                    // Buf free (prev tile's mfma done)
            {   // transpose-scatter: Vt[c][j-local] <- this thread's 32 c of row jr
                unsigned short* vd = &Buf[ch0 * 264 + jr];
                unsigned uu[8] = {u0.x, u0.y, u0.z, u0.w, u1.x, u1.y, u1.z, u1.w};
                #pragma unroll
                for (int e = 0; e < 8; e++) {
                    vd[(2 * e) * 264]     = (unsigned short)uu[e];
                    vd[(2 * e + 1) * 264] = (unsigned short)(uu[e] >> 16);
                }
                unsigned ww[8] = {u2.x, u2.y, u2.z, u2.w, u3.x, u3.y, u3.z, u3.w};
                #pragma unroll
                for (int e = 0; e < 8; e++) {
                    vd[(16 + 2 * e) * 264] = (unsigned short)ww[e];
                    vd[(17 + 2 * e) * 264] = (unsigned short)(ww[e] >> 16);
                }
            }
            __syncthreads();                    // V tile ready
            int jn = j0 + 256;
            if (jn < Npx) {
                const unsigned short* vs2 = FtB + (size_t)(jn + jr) * Cch + c0 + ch0;
                u0 = *(const uint4*)vs2;        u1 = *(const uint4*)(vs2 + 8);
                u2 = *(const uint4*)(vs2 + 16); u3 = *(const uint4*)(vs2 + 24);
            }
            #pragma unroll
            for (int js = 0; js < 256; js += 32) {
                bf16x8 af  = *(const bf16x8*)&Buf[(cgw * 16 + ml) * 264 + js + quad * 8];
                bf16x8 bfr = *(const bf16x8*)&sP[icol][j0 + js + quad * 8];
                accp = __builtin_amdgcn_mfma_f32_16x16x32_bf16(af, bfr, accp, 0, 0, 0);
            }
        }
        #pragma unroll
        for (int r = 0; r < 4; r++) {
            int cl = cgw * 16 + quad * 4 + r;
            float loc = accp[r] * rdi;
            float bp1 = sbgc[cl] + 0.7f * loc;
            float qv = bf2f(Afull[icol][c0 + cl]);
            sdb += qv * bp1;
            snb += bp1 * bp1;
            sdf += qv * sfp1c[cl];
            sqq += qv * qv;
        }
    }
    // ---- reduce partials ----
    sdb += __shfl_xor(sdb, 16);  sdb += __shfl_xor(sdb, 32);
    snb += __shfl_xor(snb, 16);  snb += __shfl_xor(snb, 32);
    sdf += __shfl_xor(sdf, 16);  sdf += __shfl_xor(sdf, 32);
    sqq += __shfl_xor(sqq, 16);  sqq += __shfl_xor(sqq, 32);
    if (quad == 0) {
        atomicAdd(&spart[icol][0], sdb);
        atomicAdd(&spart[icol][1], snb);
        atomicAdd(&spart[icol][2], sdf);
        atomicAdd(&spart[icol][3], sqq);
    }
    __syncthreads();
    if (tid < 32) {
        float db = spart[tid][0], nb = spart[tid][1];
        float df = spart[tid][2], qq = spart[tid][3];
        float nq = sqrtf(qq);
        float sb2 = 10.f * db / fmaxf(nq * sqrtf(nb), 1e-8f);
        float sf2 = 10.f * df / fmaxf(nq * nfv[b], 1e-8f);
        out[((size_t)b * 2) * Npx + i0 + tid] = sb2;
        out[((size_t)b * 2 + 1) * Npx + i0 + tid] = sf2;
    }
}

extern "C" void kernel_launch(void* const* d_in, const int* in_sizes, int n_in,
                              void* d_out, int out_size, void* d_ws, size_t ws_size,
                              hipStream_t stream) {
    const float* fq = (const float*)d_in[0];
    const float* sf = (const float*)d_in[1];
    const int* mask = (const int*)d_in[2];
    float* out = (float*)d_out;

    float* ws = (float*)d_ws;
    float* FP    = ws;                        // B*C
    float* BP    = FP + Bsz * Cch;
    float* fgp   = BP + Bsz * Cch;
    float* bgp   = fgp + Bsz * Cch;
    float* FP1   = bgp + Bsz * Cch;           // B*C
    float* nfv   = FP1 + Bsz * Cch;           // 8
    float* dsim  = nfv + 8;                   // B*N
    float* invn  = dsim + BN;
    float* wiv   = invn + BN;                 // B*N masked invn (bg selection)
    int*   nsf   = (int*)(wiv + BN);          // 8
    int*   nsb   = nsf + 8;                   // 8
    int*   jf    = nsb + 8;                   // B*N
    int*   jb    = jf + BN;                   // B*N
    unsigned short* Ft = (unsigned short*)(jb + BN);                     // 8 MB [i][c]

    k_pool<<<dim3(Cch, Bsz), 256, 0, stream>>>(sf, mask, FP, BP);
    k_predcast<<<dim3(Npx / 32, Bsz), 512, 0, stream>>>(fq, FP, BP, dsim, invn, Ft);
    k_selcompact<<<dim3(2, Bsz), 1024, 0, stream>>>(dsim, invn, Ft, FP, nsf, nsb, jf, jb, wiv, fgp, bgp, FP1, nfv);
    k_fused<<<dim3(32, Bsz), 512, 0, stream>>>(Ft, wiv, invn, bgp, FP1, nfv, out);
}

// Round 11
// 130.399 us; speedup vs baseline: 1.3984x; 1.3984x over previous
//
#include <hip/hip_runtime.h>
#include <math.h>

#define Bsz 8
#define Cch 512
#define Npx 1024
#define TOPK 12
#define BN (Bsz * Npx)

typedef __attribute__((ext_vector_type(8))) short bf16x8;
typedef __attribute__((ext_vector_type(4))) float f32x4;

__device__ __forceinline__ unsigned short f2bf(float x) {
    unsigned u = __float_as_uint(x);
    u += 0x7FFF + ((u >> 16) & 1);
    return (unsigned short)(u >> 16);
}
__device__ __forceinline__ float bf2f(unsigned short h) {
    return __uint_as_float(((unsigned)h) << 16);
}

// ---------------- reduction helpers ----------------
__device__ __forceinline__ float warp_sum64(float v) {
    for (int o = 32; o > 0; o >>= 1) v += __shfl_down(v, o);
    return v;
}
__device__ __forceinline__ float block_sum512(float v, float* s8) {
    v = warp_sum64(v);
    int lane = threadIdx.x & 63, w = threadIdx.x >> 6;
    __syncthreads();
    if (lane == 0) s8[w] = v;
    __syncthreads();
    float r = 0.f;
    #pragma unroll
    for (int k = 0; k < 8; k++) r += s8[k];
    return r;
}

// ---------------- 1: masked average pool (float4, single-barrier) -------------
// grid (Cch, Bsz), block 256
__global__ void k_pool(const float* __restrict__ sf, const int* __restrict__ mask,
                       float* __restrict__ FPo, float* __restrict__ BPo) {
    __shared__ float s4a[4], s4b[4], s4c[4];
    int c = blockIdx.x, b = blockIdx.y, t = threadIdx.x;
    const float4* f4 = (const float4*)(sf + ((size_t)b * Cch + c) * Npx);
    const int4* m4 = (const int4*)(mask + (size_t)b * Npx);
    float4 v = f4[t];
    int4 m = m4[t];
    float sumf = (m.x == 1 ? v.x : 0.f) + (m.y == 1 ? v.y : 0.f)
               + (m.z == 1 ? v.z : 0.f) + (m.w == 1 ? v.w : 0.f);
    float tot = v.x + v.y + v.z + v.w;
    float cf = (float)((m.x == 1) + (m.y == 1) + (m.z == 1) + (m.w == 1));
    sumf = warp_sum64(sumf);
    tot  = warp_sum64(tot);
    cf   = warp_sum64(cf);
    int lane = t & 63, w = t >> 6;
    if (lane == 0) { s4a[w] = sumf; s4b[w] = tot; s4c[w] = cf; }
    __syncthreads();
    if (t == 0) {
        float sA = s4a[0] + s4a[1] + s4a[2] + s4a[3];
        float sB = s4b[0] + s4b[1] + s4b[2] + s4b[3];
        float sC = s4c[0] + s4c[1] + s4c[2] + s4c[3];
        FPo[b * Cch + c] = sA / (sC + 1e-5f);
        BPo[b * Cch + c] = (sB - sA) / ((1024.f - sC) + 1e-5f);
    }
}

// ---------------- 2: pred logit + bf16 cast (block 512: 16 thr/pixel) ---------
// grid (Npx/32, Bsz), block 512.
__global__ void __launch_bounds__(512) k_predcast(const float* __restrict__ fq,
                       const float* __restrict__ FP, const float* __restrict__ BP,
                       float* __restrict__ dsim, float* __restrict__ invn,
                       unsigned short* __restrict__ Ft) {
    __shared__ float sFP[Cch], sBP[Cch], s8[8];
    __shared__ float rdf[16][32], rdb[16][32], rqq[16][32];
    __shared__ unsigned short S[32][522];   // odd dword stride -> conflict-free
    int b = blockIdx.y, t = threadIdx.x;
    int tx = t & 31, ty = t >> 5;           // ty in [0,16)
    int p0 = blockIdx.x * 32;
    int p = p0 + tx;
    sFP[t] = FP[b * Cch + t];
    sBP[t] = BP[b * Cch + t];
    __syncthreads();
    float nf = sqrtf(block_sum512(sFP[t] * sFP[t], s8));
    float nb = sqrtf(block_sum512(sBP[t] * sBP[t], s8));
    const float* q = fq + (size_t)b * Cch * Npx + p;
    float df = 0.f, db = 0.f, qq = 0.f;
    int c0 = ty * 32;
    #pragma unroll 4
    for (int c = 0; c < 32; c += 2) {
        float v0 = q[(size_t)(c0 + c) * Npx];
        float v1 = q[(size_t)(c0 + c + 1) * Npx];
        df += v0 * sFP[c0 + c] + v1 * sFP[c0 + c + 1];
        db += v0 * sBP[c0 + c] + v1 * sBP[c0 + c + 1];
        qq += v0 * v0 + v1 * v1;
        unsigned pk = (unsigned)f2bf(v0) | ((unsigned)f2bf(v1) << 16);
        *(unsigned*)&S[tx][c0 + c] = pk;
    }
    rdf[ty][tx] = df; rdb[ty][tx] = db; rqq[ty][tx] = qq;
    __syncthreads();
    for (int s = 8; s > 0; s >>= 1) {
        if (ty < s) {
            rdf[ty][tx] += rdf[ty + s][tx];
            rdb[ty][tx] += rdb[ty + s][tx];
            rqq[ty][tx] += rqq[ty + s][tx];
        }
        __syncthreads();
    }
    if (ty == 0) {
        float nq = sqrtf(rqq[0][tx]);
        float simf = 10.f * rdf[0][tx] / fmaxf(nq * nf, 1e-8f);
        float simb = 10.f * rdb[0][tx] / fmaxf(nq * nb, 1e-8f);
        dsim[b * Npx + p] = simf - simb;
        invn[b * Npx + p] = 1.f / nq;
    }
    // write Ft rows (coalesced dword stores, conflict-free LDS dword reads)
    int w = t >> 6, lane = t & 63;           // 8 waves
    unsigned short* FtB = Ft + (size_t)b * Npx * Cch;
    for (int pr = w; pr < 32; pr += 8) {
        unsigned* dst = (unsigned*)(FtB + (size_t)(p0 + pr) * Cch);
        #pragma unroll
        for (int it = 0; it < 4; it++) {
            int d = it * 64 + lane;
            dst[d] = *(const unsigned*)&S[pr][d * 2];
        }
    }
}

// ---------------- 3: select + compact + prototypes + FP1/nf -------------------
// grid (2, Bsz), block 1024 (16 waves). x=0: fg, x=1: bg
__global__ void __launch_bounds__(1024) k_selcompact(const float* __restrict__ dsim,
                        const float* __restrict__ invn,
                        const unsigned short* __restrict__ Ft,
                        const float* __restrict__ FP,
                        int* __restrict__ nsf, int* __restrict__ nsb,
                        int* __restrict__ jf, int* __restrict__ jb,
                        float* __restrict__ ivg,
                        float* __restrict__ fgp, float* __restrict__ bgp,
                        float* __restrict__ FP1, float* __restrict__ nfv) {
    __shared__ int wsum[16];
    __shared__ int sns;
    __shared__ float sProto[16][512];       // 32 KB
    __shared__ float s16f[16];
    int b = blockIdx.y, t = threadIdx.x;
    int lane = t & 63, w = t >> 6;
    bool isf = (blockIdx.x == 0);
    float d = dsim[b * Npx + t];
    float key = isf ? d : -d;
    float thres = isf ? 0.8472979f : 0.4054651f;   // ln(0.7/0.3), ln(0.6/0.4)
    int flag = (key > thres) ? 1 : 0;
    int x = flag;
    #pragma unroll
    for (int o = 1; o < 64; o <<= 1) {
        int y = __shfl_up(x, o);
        if (lane >= o) x += y;
    }
    if (lane == 63) wsum[w] = x;
    __syncthreads();
    int base = 0, total = 0;
    #pragma unroll
    for (int k = 0; k < 16; k++) {
        int s = wsum[k];
        if (k < w) base += s;
        total += s;
    }
    int* jdst = (isf ? jf : jb) + b * Npx;
    if (total == 0) {
        // cold path: top-12 fallback (lower index wins ties)
        __shared__ int   sc[Npx];
        __shared__ float v[Npx];
        __shared__ float rv[Npx];
        __shared__ int   ri[Npx];
        v[t] = key; flag = 0;
        __syncthreads();
        for (int k = 0; k < TOPK; k++) {
            rv[t] = v[t]; ri[t] = t;
            __syncthreads();
            for (int s = 512; s > 0; s >>= 1) {
                if (t < s) {
                    float a = rv[t], bb = rv[t + s];
                    int ia = ri[t], ib = ri[t + s];
                    if (bb > a || (bb == a && ib < ia)) { rv[t] = bb; ri[t] = ib; }
                }
                __syncthreads();
            }
            int win = ri[0];
            if (t == win) { flag = 1; v[t] = -INFINITY; }
            __syncthreads();
        }
        sc[t] = flag;
        __syncthreads();
        for (int off = 1; off < 1024; off <<= 1) {
            int xx = (t >= off) ? sc[t - off] : 0;
            __syncthreads();
            sc[t] += xx;
            __syncthreads();
        }
        if (flag) {
            int pos = sc[t] - 1;
            jdst[pos] = t;
            if (!isf) ivg[b * Npx + pos] = invn[b * Npx + t];
        }
        if (t == 1023) sns = sc[1023];
    } else {
        if (flag) {
            int pos = base + x - 1;
            jdst[pos] = t;
            if (!isf) ivg[b * Npx + pos] = invn[b * Npx + t];
        }
        if (t == 0) sns = total;
    }
    __syncthreads();                         // jdst writes + sns visible to block
    int ns = sns;
    if (t == 0) (isf ? nsf : nsb)[b] = ns;
    // ---- prototype: mean of selected Ft rows (coalesced 1KB row reads) ----
    const unsigned short* FtB = Ft + (size_t)b * Npx * Cch;
    float facc[8] = {0.f, 0.f, 0.f, 0.f, 0.f, 0.f, 0.f, 0.f};
    int k = w;
    int row = (k < ns) ? jdst[k] : 0;
    while (k < ns) {
        int kn = k + 16;
        int rown = (kn < ns) ? jdst[kn] : 0;   // prefetch index
        bf16x8 vv = *(const bf16x8*)&FtB[(size_t)row * Cch + lane * 8];
        #pragma unroll
        for (int e = 0; e < 8; e++) facc[e] += bf2f((unsigned short)vv[e]);
        k = kn; row = rown;
    }
    #pragma unroll
    for (int e = 0; e < 8; e++) sProto[w][lane * 8 + e] = facc[e];
    __syncthreads();
    float fp1 = 0.f;
    if (t < 512) {
        float s = 0.f;
        #pragma unroll
        for (int q = 0; q < 16; q++) s += sProto[q][t];
        float pv = s / (float)ns;
        (isf ? fgp : bgp)[b * Cch + t] = pv;
        if (isf) {
            fp1 = 0.5f * FP[b * Cch + t] + 0.5f * pv;
            FP1[b * Cch + t] = fp1;
        }
    }
    if (isf) {
        // ||FP1|| for the final fg similarity
        float v2 = warp_sum64(fp1 * fp1);
        if (lane == 0) s16f[w] = v2;
        __syncthreads();
        if (t == 0) {
            float nn = 0.f;
            #pragma unroll
            for (int q = 0; q < 16; q++) nn += s16f[q];
            nfv[b] = sqrtf(nn);
        }
    }
}

// ---------------- 4: FUSED gram + softmax + PV + finalize (compacted-j) -------
// grid 256 (1D), block 512 (8 waves), ~123 KB LDS.
// XCD batch swizzle: b = bid & 7, i0 = (bid>>3)*32 -- under round-robin
// block->XCD dispatch, all 32 blocks of batch b land on XCD b, making the
// 1 MB per-batch Ft slice L2-resident (R10 counters showed the non-swizzled
// layout thrashes L2: 68.5 MB HBM refetch at 762 GB/s).
__global__ void __launch_bounds__(512) k_fused(
        const unsigned short* __restrict__ Ft,
        const int* __restrict__ jb, const int* __restrict__ nsb,
        const float* __restrict__ invn, const float* __restrict__ ivg,
        const float* __restrict__ bgp, const float* __restrict__ FP1,
        const float* __restrict__ nfv, float* __restrict__ out) {
    __shared__ unsigned short Afull[32][520];   // q rows, full K (33.3 KB)
    __shared__ unsigned short sP[32][1032];     // attention rows (66 KB)
    __shared__ unsigned short Bt[64][136];      // gram-B / V-transpose staging (17.4 KB)
    __shared__ int   sji[1024];
    __shared__ float sfj[1024];
    __shared__ float sfi[32], sden[32];
    __shared__ float sfp1c[64], sbgc[64];
    __shared__ float spart[32][4];

    int bid = blockIdx.x;
    int b = bid & 7;                       // batch -> XCD (round-robin heuristic)
    int i0 = (bid >> 3) * 32;
    int tid = threadIdx.x;
    int l = tid & 63, w = tid >> 6;
    int ml = l & 15, quad = l >> 4;
    int ns = nsb[b];
    int K64 = ((((ns + 31) & ~31) + 63) & ~63);

    const unsigned short* FtB = Ft + (size_t)b * Npx * Cch;

    // ---- stage A (q rows, full K) + index/scale tables ----
    #pragma unroll
    for (int s = 0; s < 4; s++) {
        int idx = tid + s * 512;
        int row = idx >> 6, kc8 = (idx & 63) * 8;
        *(uint4*)&Afull[row][kc8] = *(const uint4*)(FtB + (size_t)(i0 + row) * Cch + kc8);
    }
    for (int j = tid; j < K64; j += 512) {
        sji[j] = (j < ns) ? jb[b * Npx + j] : jb[b * Npx];
        sfj[j] = (j < ns) ? ivg[b * Npx + j] : 0.f;
    }
    if (tid < 32) sfi[tid] = 2.f * invn[b * Npx + i0 + tid];
    __syncthreads();

    // ---- phase 1: gram rows -> sP = exp(sim) (bf16) ----
    int ig = w & 1, jg = w >> 1;            // 8 waves tile 32i x 64j
    for (int j0 = 0; j0 < K64; j0 += 64) {
        const unsigned short* pb0 = FtB + (size_t)sji[j0 + (tid >> 4)] * Cch + (tid & 15) * 8;
        const unsigned short* pb1 = FtB + (size_t)sji[j0 + 32 + (tid >> 4)] * Cch + (tid & 15) * 8;
        uint4 v0 = *(const uint4*)pb0;
        uint4 v1 = *(const uint4*)pb1;
        f32x4 acc = {};
        for (int k0 = 0; k0 < Cch; k0 += 128) {
            __syncthreads();
            *(uint4*)&Bt[tid >> 4][(tid & 15) * 8] = v0;
            *(uint4*)&Bt[32 + (tid >> 4)][(tid & 15) * 8] = v1;
            __syncthreads();
            int kn = k0 + 128;
            if (kn < Cch) {
                v0 = *(const uint4*)(pb0 + kn);
                v1 = *(const uint4*)(pb1 + kn);
            }
            #pragma unroll
            for (int h = 0; h < 4; h++) {
                bf16x8 af = *(const bf16x8*)&Afull[ig * 16 + ml][k0 + h * 32 + quad * 8];
                bf16x8 bf = *(const bf16x8*)&Bt[jg * 16 + ml][h * 32 + quad * 8];
                acc = __builtin_amdgcn_mfma_f32_16x16x32_bf16(af, bf, acc, 0, 0, 0);
            }
        }
        #pragma unroll
        for (int r = 0; r < 4; r++) {
            int il = ig * 16 + quad * 4 + r;
            int jl = jg * 16 + ml;
            float e = (j0 + jl < ns) ? __expf(acc[r] * sfi[il] * sfj[j0 + jl]) : 0.f;
            sP[il][j0 + jl] = f2bf(e);
        }
    }
    __syncthreads();

    // ---- row denominators from sP + zero partial sums ----
    {
        int i = tid >> 4, jj16 = tid & 15;
        float s = 0.f;
        for (int j = jj16; j < K64; j += 16) s += bf2f(sP[i][j]);
        #pragma unroll
        for (int m = 1; m < 16; m <<= 1) s += __shfl_xor(s, m);
        if (jj16 == 0) sden[i] = s;
    }
    if (tid < 128) ((float*)spart)[tid] = 0.f;
    __syncthreads();

    // ---- phase 2: PV over all c + similarity partials ----
    int cgw = w & 3, igw = w >> 2;
    int icol = igw * 16 + ml;               // local i this lane accumulates
    float rdi = 1.f / sden[icol];
    float sdb = 0.f, snb = 0.f, sdf = 0.f, sqq = 0.f;
    int jj = tid & 63, cg = tid >> 6;
    for (int c0 = 0; c0 < Cch; c0 += 64) {
        __syncthreads();                    // protect sfp1c/sbgc + Bt reuse
        if (tid < 64) {
            sfp1c[tid] = FP1[b * Cch + c0 + tid];
            sbgc[tid]  = 0.3f * bgp[b * Cch + c0 + tid];
        }
        f32x4 accp = {};
        uint4 vv = *(const uint4*)(FtB + (size_t)sji[jj] * Cch + c0 + cg * 8);
        for (int j0 = 0; j0 < K64; j0 += 64) {
            __syncthreads();                // Bt free
            {   // gather-transpose: Bt[c][j] <- Ft[ji[j]][c]
                unsigned short* qd = &Bt[cg * 8][jj];
                qd[0]       = (unsigned short)vv.x;  qd[136]     = (unsigned short)(vv.x >> 16);
                qd[2 * 136] = (unsigned short)vv.y;  qd[3 * 136] = (unsigned short)(vv.y >> 16);
                qd[4 * 136] = (unsigned short)vv.z;  qd[5 * 136] = (unsigned short)(vv.z >> 16);
                qd[6 * 136] = (unsigned short)vv.w;  qd[7 * 136] = (unsigned short)(vv.w >> 16);
            }
            __syncthreads();                // V tile ready
            int jn = j0 + 64;
            if (jn < K64) vv = *(const uint4*)(FtB + (size_t)sji[jn + jj] * Cch + c0 + cg * 8);
            #pragma unroll
            for (int hh = 0; hh < 2; hh++) {
                bf16x8 af  = *(const bf16x8*)&Bt[cgw * 16 + ml][hh * 32 + quad * 8];
                bf16x8 bfr = *(const bf16x8*)&sP[icol][j0 + hh * 32 + quad * 8];
                accp = __builtin_amdgcn_mfma_f32_16x16x32_bf16(af, bfr, accp, 0, 0, 0);
            }
        }
        #pragma unroll
        for (int r = 0; r < 4; r++) {
            int cl = cgw * 16 + quad * 4 + r;
            float loc = accp[r] * rdi;
            float bp1 = sbgc[cl] + 0.7f * loc;
            float qv = bf2f(Afull[icol][c0 + cl]);
            sdb += qv * bp1;
            snb += bp1 * bp1;
            sdf += qv * sfp1c[cl];
            sqq += qv * qv;
        }
    }
    // ---- reduce partials (quads within wave, then cross-wave via LDS) ----
    sdb += __shfl_xor(sdb, 16);  sdb += __shfl_xor(sdb, 32);
    snb += __shfl_xor(snb, 16);  snb += __shfl_xor(snb, 32);
    sdf += __shfl_xor(sdf, 16);  sdf += __shfl_xor(sdf, 32);
    sqq += __shfl_xor(sqq, 16);  sqq += __shfl_xor(sqq, 32);
    if (quad == 0) {
        atomicAdd(&spart[icol][0], sdb);
        atomicAdd(&spart[icol][1], snb);
        atomicAdd(&spart[icol][2], sdf);
        atomicAdd(&spart[icol][3], sqq);
    }
    __syncthreads();
    if (tid < 32) {
        float db = spart[tid][0], nb = spart[tid][1];
        float df = spart[tid][2], qq = spart[tid][3];
        float nq = sqrtf(qq);
        float sb2 = 10.f * db / fmaxf(nq * sqrtf(nb), 1e-8f);
        float sf2 = 10.f * df / fmaxf(nq * nfv[b], 1e-8f);
        out[((size_t)b * 2) * Npx + i0 + tid] = sb2;
        out[((size_t)b * 2 + 1) * Npx + i0 + tid] = sf2;
    }
}

extern "C" void kernel_launch(void* const* d_in, const int* in_sizes, int n_in,
                              void* d_out, int out_size, void* d_ws, size_t ws_size,
                              hipStream_t stream) {
    const float* fq = (const float*)d_in[0];
    const float* sf = (const float*)d_in[1];
    const int* mask = (const int*)d_in[2];
    float* out = (float*)d_out;

    float* ws = (float*)d_ws;
    float* FP    = ws;                        // B*C
    float* BP    = FP + Bsz * Cch;
    float* fgp   = BP + Bsz * Cch;
    float* bgp   = fgp + Bsz * Cch;
    float* FP1   = bgp + Bsz * Cch;           // B*C
    float* nfv   = FP1 + Bsz * Cch;           // 8
    float* dsim  = nfv + 8;                   // B*N
    float* invn  = dsim + BN;
    float* ivg   = invn + BN;
    int*   nsf   = (int*)(ivg + BN);          // 8
    int*   nsb   = nsf + 8;                   // 8
    int*   jf    = nsb + 8;                   // B*N
    int*   jb    = jf + BN;                   // B*N
    unsigned short* Ft = (unsigned short*)(jb + BN);                     // 8 MB [i][c]

    k_pool<<<dim3(Cch, Bsz), 256, 0, stream>>>(sf, mask, FP, BP);
    k_predcast<<<dim3(Npx / 32, Bsz), 512, 0, stream>>>(fq, FP, BP, dsim, invn, Ft);
    k_selcompact<<<dim3(2, Bsz), 1024, 0, stream>>>(dsim, invn, Ft, FP, nsf, nsb, jf, jb, ivg, fgp, bgp, FP1, nfv);
    k_fused<<<dim3(256), 512, 0, stream>>>(Ft, jb, nsb, invn, ivg, bgp, FP1, nfv, out);
}

// Round 12
// 126.471 us; speedup vs baseline: 1.4419x; 1.0311x over previous
//
#include <hip/hip_runtime.h>
#include <math.h>

#define Bsz 8
#define Cch 512
#define Npx 1024
#define TOPK 12
#define BN (Bsz * Npx)

typedef __attribute__((ext_vector_type(8))) short bf16x8;
typedef __attribute__((ext_vector_type(4))) float f32x4;

__device__ __forceinline__ unsigned short f2bf(float x) {
    unsigned u = __float_as_uint(x);
    u += 0x7FFF + ((u >> 16) & 1);
    return (unsigned short)(u >> 16);
}
__device__ __forceinline__ float bf2f(unsigned short h) {
    return __uint_as_float(((unsigned)h) << 16);
}

// ---------------- reduction helpers ----------------
__device__ __forceinline__ float warp_sum64(float v) {
    for (int o = 32; o > 0; o >>= 1) v += __shfl_down(v, o);
    return v;
}
__device__ __forceinline__ float block_sum512(float v, float* s8) {
    v = warp_sum64(v);
    int lane = threadIdx.x & 63, w = threadIdx.x >> 6;
    __syncthreads();
    if (lane == 0) s8[w] = v;
    __syncthreads();
    float r = 0.f;
    #pragma unroll
    for (int k = 0; k < 8; k++) r += s8[k];
    return r;
}

// ---------------- 1: masked average pool (float4, single-barrier) -------------
// grid (Cch, Bsz), block 256
__global__ void k_pool(const float* __restrict__ sf, const int* __restrict__ mask,
                       float* __restrict__ FPo, float* __restrict__ BPo) {
    __shared__ float s4a[4], s4b[4], s4c[4];
    int c = blockIdx.x, b = blockIdx.y, t = threadIdx.x;
    const float4* f4 = (const float4*)(sf + ((size_t)b * Cch + c) * Npx);
    const int4* m4 = (const int4*)(mask + (size_t)b * Npx);
    float4 v = f4[t];
    int4 m = m4[t];
    float sumf = (m.x == 1 ? v.x : 0.f) + (m.y == 1 ? v.y : 0.f)
               + (m.z == 1 ? v.z : 0.f) + (m.w == 1 ? v.w : 0.f);
    float tot = v.x + v.y + v.z + v.w;
    float cf = (float)((m.x == 1) + (m.y == 1) + (m.z == 1) + (m.w == 1));
    sumf = warp_sum64(sumf);
    tot  = warp_sum64(tot);
    cf   = warp_sum64(cf);
    int lane = t & 63, w = t >> 6;
    if (lane == 0) { s4a[w] = sumf; s4b[w] = tot; s4c[w] = cf; }
    __syncthreads();
    if (t == 0) {
        float sA = s4a[0] + s4a[1] + s4a[2] + s4a[3];
        float sB = s4b[0] + s4b[1] + s4b[2] + s4b[3];
        float sC = s4c[0] + s4c[1] + s4c[2] + s4c[3];
        FPo[b * Cch + c] = sA / (sC + 1e-5f);
        BPo[b * Cch + c] = (sB - sA) / ((1024.f - sC) + 1e-5f);
    }
}

// ---------------- 2: pred logit + bf16 cast (block 512: 16 thr/pixel) ---------
// grid (Npx/32, Bsz), block 512.
__global__ void __launch_bounds__(512) k_predcast(const float* __restrict__ fq,
                       const float* __restrict__ FP, const float* __restrict__ BP,
                       float* __restrict__ dsim, float* __restrict__ invn,
                       unsigned short* __restrict__ Ft) {
    __shared__ float sFP[Cch], sBP[Cch], s8[8];
    __shared__ float rdf[16][32], rdb[16][32], rqq[16][32];
    __shared__ unsigned short S[32][522];   // odd dword stride -> conflict-free
    int b = blockIdx.y, t = threadIdx.x;
    int tx = t & 31, ty = t >> 5;           // ty in [0,16)
    int p0 = blockIdx.x * 32;
    int p = p0 + tx;
    sFP[t] = FP[b * Cch + t];
    sBP[t] = BP[b * Cch + t];
    __syncthreads();
    float nf = sqrtf(block_sum512(sFP[t] * sFP[t], s8));
    float nb = sqrtf(block_sum512(sBP[t] * sBP[t], s8));
    const float* q = fq + (size_t)b * Cch * Npx + p;
    float df = 0.f, db = 0.f, qq = 0.f;
    int c0 = ty * 32;
    #pragma unroll 4
    for (int c = 0; c < 32; c += 2) {
        float v0 = q[(size_t)(c0 + c) * Npx];
        float v1 = q[(size_t)(c0 + c + 1) * Npx];
        df += v0 * sFP[c0 + c] + v1 * sFP[c0 + c + 1];
        db += v0 * sBP[c0 + c] + v1 * sBP[c0 + c + 1];
        qq += v0 * v0 + v1 * v1;
        unsigned pk = (unsigned)f2bf(v0) | ((unsigned)f2bf(v1) << 16);
        *(unsigned*)&S[tx][c0 + c] = pk;
    }
    rdf[ty][tx] = df; rdb[ty][tx] = db; rqq[ty][tx] = qq;
    __syncthreads();
    for (int s = 8; s > 0; s >>= 1) {
        if (ty < s) {
            rdf[ty][tx] += rdf[ty + s][tx];
            rdb[ty][tx] += rdb[ty + s][tx];
            rqq[ty][tx] += rqq[ty + s][tx];
        }
        __syncthreads();
    }
    if (ty == 0) {
        float nq = sqrtf(rqq[0][tx]);
        float simf = 10.f * rdf[0][tx] / fmaxf(nq * nf, 1e-8f);
        float simb = 10.f * rdb[0][tx] / fmaxf(nq * nb, 1e-8f);
        dsim[b * Npx + p] = simf - simb;
        invn[b * Npx + p] = 1.f / nq;
    }
    // write Ft rows (coalesced dword stores, conflict-free LDS dword reads)
    int w = t >> 6, lane = t & 63;           // 8 waves
    unsigned short* FtB = Ft + (size_t)b * Npx * Cch;
    for (int pr = w; pr < 32; pr += 8) {
        unsigned* dst = (unsigned*)(FtB + (size_t)(p0 + pr) * Cch);
        #pragma unroll
        for (int it = 0; it < 4; it++) {
            int d = it * 64 + lane;
            dst[d] = *(const unsigned*)&S[pr][d * 2];
        }
    }
}

// ---------------- 3: select + compact + prototypes + FP1/nf -------------------
// grid (2, Bsz), block 1024 (16 waves). x=0: fg, x=1: bg
__global__ void __launch_bounds__(1024) k_selcompact(const float* __restrict__ dsim,
                        const float* __restrict__ invn,
                        const unsigned short* __restrict__ Ft,
                        const float* __restrict__ FP,
                        int* __restrict__ nsf, int* __restrict__ nsb,
                        int* __restrict__ jf, int* __restrict__ jb,
                        float* __restrict__ ivg,
                        float* __restrict__ fgp, float* __restrict__ bgp,
                        float* __restrict__ FP1, float* __restrict__ nfv) {
    __shared__ int wsum[16];
    __shared__ int sns;
    __shared__ float sProto[16][512];       // 32 KB
    __shared__ float s16f[16];
    int b = blockIdx.y, t = threadIdx.x;
    int lane = t & 63, w = t >> 6;
    bool isf = (blockIdx.x == 0);
    float d = dsim[b * Npx + t];
    float key = isf ? d : -d;
    float thres = isf ? 0.8472979f : 0.4054651f;   // ln(0.7/0.3), ln(0.6/0.4)
    int flag = (key > thres) ? 1 : 0;
    int x = flag;
    #pragma unroll
    for (int o = 1; o < 64; o <<= 1) {
        int y = __shfl_up(x, o);
        if (lane >= o) x += y;
    }
    if (lane == 63) wsum[w] = x;
    __syncthreads();
    int base = 0, total = 0;
    #pragma unroll
    for (int k = 0; k < 16; k++) {
        int s = wsum[k];
        if (k < w) base += s;
        total += s;
    }
    int* jdst = (isf ? jf : jb) + b * Npx;
    if (total == 0) {
        // cold path: top-12 fallback (lower index wins ties)
        __shared__ int   sc[Npx];
        __shared__ float v[Npx];
        __shared__ float rv[Npx];
        __shared__ int   ri[Npx];
        v[t] = key; flag = 0;
        __syncthreads();
        for (int k = 0; k < TOPK; k++) {
            rv[t] = v[t]; ri[t] = t;
            __syncthreads();
            for (int s = 512; s > 0; s >>= 1) {
                if (t < s) {
                    float a = rv[t], bb = rv[t + s];
                    int ia = ri[t], ib = ri[t + s];
                    if (bb > a || (bb == a && ib < ia)) { rv[t] = bb; ri[t] = ib; }
                }
                __syncthreads();
            }
            int win = ri[0];
            if (t == win) { flag = 1; v[t] = -INFINITY; }
            __syncthreads();
        }
        sc[t] = flag;
        __syncthreads();
        for (int off = 1; off < 1024; off <<= 1) {
            int xx = (t >= off) ? sc[t - off] : 0;
            __syncthreads();
            sc[t] += xx;
            __syncthreads();
        }
        if (flag) {
            int pos = sc[t] - 1;
            jdst[pos] = t;
            if (!isf) ivg[b * Npx + pos] = invn[b * Npx + t];
        }
        if (t == 1023) sns = sc[1023];
    } else {
        if (flag) {
            int pos = base + x - 1;
            jdst[pos] = t;
            if (!isf) ivg[b * Npx + pos] = invn[b * Npx + t];
        }
        if (t == 0) sns = total;
    }
    __syncthreads();                         // jdst writes + sns visible to block
    int ns = sns;
    if (t == 0) (isf ? nsf : nsb)[b] = ns;
    // ---- prototype: mean of selected Ft rows (coalesced 1KB row reads) ----
    const unsigned short* FtB = Ft + (size_t)b * Npx * Cch;
    float facc[8] = {0.f, 0.f, 0.f, 0.f, 0.f, 0.f, 0.f, 0.f};
    int k = w;
    int row = (k < ns) ? jdst[k] : 0;
    while (k < ns) {
        int kn = k + 16;
        int rown = (kn < ns) ? jdst[kn] : 0;   // prefetch index
        bf16x8 vv = *(const bf16x8*)&FtB[(size_t)row * Cch + lane * 8];
        #pragma unroll
        for (int e = 0; e < 8; e++) facc[e] += bf2f((unsigned short)vv[e]);
        k = kn; row = rown;
    }
    #pragma unroll
    for (int e = 0; e < 8; e++) sProto[w][lane * 8 + e] = facc[e];
    __syncthreads();
    float fp1 = 0.f;
    if (t < 512) {
        float s = 0.f;
        #pragma unroll
        for (int q = 0; q < 16; q++) s += sProto[q][t];
        float pv = s / (float)ns;
        (isf ? fgp : bgp)[b * Cch + t] = pv;
        if (isf) {
            fp1 = 0.5f * FP[b * Cch + t] + 0.5f * pv;
            FP1[b * Cch + t] = fp1;
        }
    }
    if (isf) {
        // ||FP1|| for the final fg similarity
        float v2 = warp_sum64(fp1 * fp1);
        if (lane == 0) s16f[w] = v2;
        __syncthreads();
        if (t == 0) {
            float nn = 0.f;
            #pragma unroll
            for (int q = 0; q < 16; q++) nn += s16f[q];
            nfv[b] = sqrtf(nn);
        }
    }
}

// ---------------- 4: FUSED gram + softmax + PV + finalize (compacted-j) -------
// grid 256 (1D, batch->XCD swizzle), block 512 (8 waves), ~144 KB LDS.
// R12: double-buffered Bt in both phases (single barrier per iteration --
// scatter into buf, bar, mfma buf; prior readers of buf are 2 iters back,
// protected by the intervening barrier), gather prefetch issued before the
// barrier so HBM/L2 latency hides under MFMA, FP1/bgp preloaded in full.
__global__ void __launch_bounds__(512) k_fused(
        const unsigned short* __restrict__ Ft,
        const int* __restrict__ jb, const int* __restrict__ nsb,
        const float* __restrict__ invn, const float* __restrict__ ivg,
        const float* __restrict__ bgp, const float* __restrict__ FP1,
        const float* __restrict__ nfv, float* __restrict__ out) {
    __shared__ unsigned short Afull[32][520];   // q rows, full K (33.3 KB)
    __shared__ unsigned short sP[32][1032];     // attention rows (66 KB)
    __shared__ unsigned short Bt2[2][64][136];  // dbuf gram-B / V-transpose (34.8 KB)
    __shared__ int   sji[1024];
    __shared__ float sfj[1024];
    __shared__ float sfp1full[Cch], sbgfull[Cch];  // 4 KB
    __shared__ float sfi[32], sden[32];
    __shared__ float spart[32][4];

    int bid = blockIdx.x;
    int b = bid & 7;                       // batch -> XCD (round-robin heuristic)
    int i0 = (bid >> 3) * 32;
    int tid = threadIdx.x;
    int l = tid & 63, w = tid >> 6;
    int ml = l & 15, quad = l >> 4;
    int ns = nsb[b];
    int K64 = ((((ns + 31) & ~31) + 63) & ~63);
    int T = K64 >> 6;

    const unsigned short* FtB = Ft + (size_t)b * Npx * Cch;

    // ---- stage A (q rows, full K) + tables + full FP1/bgp preload ----
    #pragma unroll
    for (int s = 0; s < 4; s++) {
        int idx = tid + s * 512;
        int row = idx >> 6, kc8 = (idx & 63) * 8;
        *(uint4*)&Afull[row][kc8] = *(const uint4*)(FtB + (size_t)(i0 + row) * Cch + kc8);
    }
    for (int j = tid; j < K64; j += 512) {
        sji[j] = (j < ns) ? jb[b * Npx + j] : jb[b * Npx];
        sfj[j] = (j < ns) ? ivg[b * Npx + j] : 0.f;
    }
    sfp1full[tid] = FP1[b * Cch + tid];
    sbgfull[tid]  = 0.3f * bgp[b * Cch + tid];
    if (tid < 32) sfi[tid] = 2.f * invn[b * Npx + i0 + tid];
    __syncthreads();

    // ---- phase 1: gram rows -> sP = exp(sim) (bf16); dbuf Bt, 1 bar/k-chunk --
    int ig = w & 1, jg = w >> 1;            // 8 waves tile 32i x 64j
    int grow = tid >> 4, gk8 = (tid & 15) * 8;  // staging: rows grow & grow+32
    for (int j0 = 0; j0 < K64; j0 += 64) {
        const unsigned short* pb0 = FtB + (size_t)sji[j0 + grow] * Cch + gk8;
        const unsigned short* pb1 = FtB + (size_t)sji[j0 + 32 + grow] * Cch + gk8;
        uint4 v0 = *(const uint4*)pb0;
        uint4 v1 = *(const uint4*)pb1;
        f32x4 acc = {};
        #pragma unroll
        for (int kt = 0; kt < 4; kt++) {    // Cch/128 chunks
            int buf = kt & 1;
            *(uint4*)&Bt2[buf][grow][gk8] = v0;
            *(uint4*)&Bt2[buf][32 + grow][gk8] = v1;
            int kn = (kt + 1) * 128;
            if (kn < Cch) {                 // prefetch next chunk (in flight over mfma)
                v0 = *(const uint4*)(pb0 + kn);
                v1 = *(const uint4*)(pb1 + kn);
            }
            __syncthreads();                // scatter(buf) visible; readers of buf
                                            // from kt-2 finished before bar(kt-1)
            int k0 = kt * 128;
            #pragma unroll
            for (int h = 0; h < 4; h++) {
                bf16x8 af = *(const bf16x8*)&Afull[ig * 16 + ml][k0 + h * 32 + quad * 8];
                bf16x8 bf = *(const bf16x8*)&Bt2[buf][jg * 16 + ml][h * 32 + quad * 8];
                acc = __builtin_amdgcn_mfma_f32_16x16x32_bf16(af, bf, acc, 0, 0, 0);
            }
        }
        #pragma unroll
        for (int r = 0; r < 4; r++) {
            int il = ig * 16 + quad * 4 + r;
            int jl = jg * 16 + ml;
            float e = (j0 + jl < ns) ? __expf(acc[r] * sfi[il] * sfj[j0 + jl]) : 0.f;
            sP[il][j0 + jl] = f2bf(e);
        }
        // j0 transition safety: next kt=0 scatters buf0; its last readers were
        // this tile's kt=2 mfma, before the kt=3 barrier. kt=3's buf1 readers
        // finish before next tile's kt=0 barrier (disjoint buf0 scatter first).
    }
    __syncthreads();

    // ---- row denominators from sP + zero partial sums ----
    {
        int i = tid >> 4, jj16 = tid & 15;
        float s = 0.f;
        for (int j = jj16; j < K64; j += 16) s += bf2f(sP[i][j]);
        #pragma unroll
        for (int m = 1; m < 16; m <<= 1) s += __shfl_xor(s, m);
        if (jj16 == 0) sden[i] = s;
    }
    if (tid < 128) ((float*)spart)[tid] = 0.f;
    __syncthreads();

    // ---- phase 2: PV over all c; dbuf Vt, 1 bar/j-tile + 1 bar/c0 ----
    int cgw = w & 3, igw = w >> 2;
    int icol = igw * 16 + ml;               // local i this lane accumulates
    float rdi = 1.f / sden[icol];
    float sdb = 0.f, snb = 0.f, sdf = 0.f, sqq = 0.f;
    int jj = tid & 63, cg = tid >> 6;
    for (int c0 = 0; c0 < Cch; c0 += 64) {
        f32x4 accp = {};
        uint4 vv = *(const uint4*)(FtB + (size_t)sji[jj] * Cch + c0 + cg * 8);
        for (int jt = 0; jt < T; jt++) {
            int buf = jt & 1;
            {   // gather-transpose: Vt[buf][c][j] <- Ft[ji[j]][c]
                unsigned short* qd = &Bt2[buf][cg * 8][jj];
                qd[0]       = (unsigned short)vv.x;  qd[136]     = (unsigned short)(vv.x >> 16);
                qd[2 * 136] = (unsigned short)vv.y;  qd[3 * 136] = (unsigned short)(vv.y >> 16);
                qd[4 * 136] = (unsigned short)vv.z;  qd[5 * 136] = (unsigned short)(vv.z >> 16);
                qd[6 * 136] = (unsigned short)vv.w;  qd[7 * 136] = (unsigned short)(vv.w >> 16);
            }
            if (jt + 1 < T)                 // prefetch next j-tile's gather
                vv = *(const uint4*)(FtB + (size_t)sji[(jt + 1) * 64 + jj] * Cch + c0 + cg * 8);
            __syncthreads();                // scatter(buf) visible; readers of buf
                                            // from jt-2 finished before bar(jt-1)
            int j0 = jt * 64;
            #pragma unroll
            for (int hh = 0; hh < 2; hh++) {
                bf16x8 af  = *(const bf16x8*)&Bt2[buf][cgw * 16 + ml][hh * 32 + quad * 8];
                bf16x8 bfr = *(const bf16x8*)&sP[icol][j0 + hh * 32 + quad * 8];
                accp = __builtin_amdgcn_mfma_f32_16x16x32_bf16(af, bfr, accp, 0, 0, 0);
            }
        }
        #pragma unroll
        for (int r = 0; r < 4; r++) {
            int cl = c0 + cgw * 16 + quad * 4 + r;
            float loc = accp[r] * rdi;
            float bp1 = sbgfull[cl] + 0.7f * loc;
            float qv = bf2f(Afull[icol][cl]);
            sdb += qv * bp1;
            snb += bp1 * bp1;
            sdf += qv * sfp1full[cl];
            sqq += qv * qv;
        }
        __syncthreads();                    // all mfma(buf*) done before next c0's
                                            // first scatter (T-odd parity wrap)
    }
    // ---- reduce partials (quads within wave, then cross-wave via LDS) ----
    sdb += __shfl_xor(sdb, 16);  sdb += __shfl_xor(sdb, 32);
    snb += __shfl_xor(snb, 16);  snb += __shfl_xor(snb, 32);
    sdf += __shfl_xor(sdf, 16);  sdf += __shfl_xor(sdf, 32);
    sqq += __shfl_xor(sqq, 16);  sqq += __shfl_xor(sqq, 32);
    if (quad == 0) {
        atomicAdd(&spart[icol][0], sdb);
        atomicAdd(&spart[icol][1], snb);
        atomicAdd(&spart[icol][2], sdf);
        atomicAdd(&spart[icol][3], sqq);
    }
    __syncthreads();
    if (tid < 32) {
        float db = spart[tid][0], nb = spart[tid][1];
        float df = spart[tid][2], qq = spart[tid][3];
        float nq = sqrtf(qq);
        float sb2 = 10.f * db / fmaxf(nq * sqrtf(nb), 1e-8f);
        float sf2 = 10.f * df / fmaxf(nq * nfv[b], 1e-8f);
        out[((size_t)b * 2) * Npx + i0 + tid] = sb2;
        out[((size_t)b * 2 + 1) * Npx + i0 + tid] = sf2;
    }
}

extern "C" void kernel_launch(void* const* d_in, const int* in_sizes, int n_in,
                              void* d_out, int out_size, void* d_ws, size_t ws_size,
                              hipStream_t stream) {
    const float* fq = (const float*)d_in[0];
    const float* sf = (const float*)d_in[1];
    const int* mask = (const int*)d_in[2];
    float* out = (float*)d_out;

    float* ws = (float*)d_ws;
    float* FP    = ws;                        // B*C
    float* BP    = FP + Bsz * Cch;
    float* fgp   = BP + Bsz * Cch;
    float* bgp   = fgp + Bsz * Cch;
    float* FP1   = bgp + Bsz * Cch;           // B*C
    float* nfv   = FP1 + Bsz * Cch;           // 8
    float* dsim  = nfv + 8;                   // B*N
    float* invn  = dsim + BN;
    float* ivg   = invn + BN;
    int*   nsf   = (int*)(ivg + BN);          // 8
    int*   nsb   = nsf + 8;                   // 8
    int*   jf    = nsb + 8;                   // B*N
    int*   jb    = jf + BN;                   // B*N
    unsigned short* Ft = (unsigned short*)(jb + BN);                     // 8 MB [i][c]

    k_pool<<<dim3(Cch, Bsz), 256, 0, stream>>>(sf, mask, FP, BP);
    k_predcast<<<dim3(Npx / 32, Bsz), 512, 0, stream>>>(fq, FP, BP, dsim, invn, Ft);
    k_selcompact<<<dim3(2, Bsz), 1024, 0, stream>>>(dsim, invn, Ft, FP, nsf, nsb, jf, jb, ivg, fgp, bgp, FP1, nfv);
    k_fused<<<dim3(256), 512, 0, stream>>>(Ft, jb, nsb, invn, ivg, bgp, FP1, nfv, out);
}

// Round 14
// 125.107 us; speedup vs baseline: 1.4576x; 1.0109x over previous
//
#include <hip/hip_runtime.h>
#include <math.h>

#define Bsz 8
#define Cch 512
#define Npx 1024
#define TOPK 12
#define BN (Bsz * Npx)

typedef __attribute__((ext_vector_type(8))) short bf16x8;
typedef __attribute__((ext_vector_type(4))) float f32x4;

__device__ __forceinline__ unsigned short f2bf(float x) {
    unsigned u = __float_as_uint(x);
    u += 0x7FFF + ((u >> 16) & 1);
    return (unsigned short)(u >> 16);
}
__device__ __forceinline__ float bf2f(unsigned short h) {
    return __uint_as_float(((unsigned)h) << 16);
}

// ---------------- reduction helpers ----------------
__device__ __forceinline__ float warp_sum64(float v) {
    for (int o = 32; o > 0; o >>= 1) v += __shfl_down(v, o);
    return v;
}
__device__ __forceinline__ float block_sum512(float v, float* s8) {
    v = warp_sum64(v);
    int lane = threadIdx.x & 63, w = threadIdx.x >> 6;
    __syncthreads();
    if (lane == 0) s8[w] = v;
    __syncthreads();
    float r = 0.f;
    #pragma unroll
    for (int k = 0; k < 8; k++) r += s8[k];
    return r;
}

// ---------------- 1: masked average pool (float4, single-barrier) -------------
// grid (Cch, Bsz), block 256
__global__ void k_pool(const float* __restrict__ sf, const int* __restrict__ mask,
                       float* __restrict__ FPo, float* __restrict__ BPo) {
    __shared__ float s4a[4], s4b[4], s4c[4];
    int c = blockIdx.x, b = blockIdx.y, t = threadIdx.x;
    const float4* f4 = (const float4*)(sf + ((size_t)b * Cch + c) * Npx);
    const int4* m4 = (const int4*)(mask + (size_t)b * Npx);
    float4 v = f4[t];
    int4 m = m4[t];
    float sumf = (m.x == 1 ? v.x : 0.f) + (m.y == 1 ? v.y : 0.f)
               + (m.z == 1 ? v.z : 0.f) + (m.w == 1 ? v.w : 0.f);
    float tot = v.x + v.y + v.z + v.w;
    float cf = (float)((m.x == 1) + (m.y == 1) + (m.z == 1) + (m.w == 1));
    sumf = warp_sum64(sumf);
    tot  = warp_sum64(tot);
    cf   = warp_sum64(cf);
    int lane = t & 63, w = t >> 6;
    if (lane == 0) { s4a[w] = sumf; s4b[w] = tot; s4c[w] = cf; }
    __syncthreads();
    if (t == 0) {
        float sA = s4a[0] + s4a[1] + s4a[2] + s4a[3];
        float sB = s4b[0] + s4b[1] + s4b[2] + s4b[3];
        float sC = s4c[0] + s4c[1] + s4c[2] + s4c[3];
        FPo[b * Cch + c] = sA / (sC + 1e-5f);
        BPo[b * Cch + c] = (sB - sA) / ((1024.f - sC) + 1e-5f);
    }
}

// ---------------- 2: pred logit + bf16 cast (block 512: 16 thr/pixel) ---------
// grid (Npx/32, Bsz), block 512.
__global__ void __launch_bounds__(512) k_predcast(const float* __restrict__ fq,
                       const float* __restrict__ FP, const float* __restrict__ BP,
                       float* __restrict__ dsim, float* __restrict__ invn,
                       unsigned short* __restrict__ Ft) {
    __shared__ float sFP[Cch], sBP[Cch], s8[8];
    __shared__ float rdf[16][32], rdb[16][32], rqq[16][32];
    __shared__ unsigned short S[32][522];   // odd dword stride -> conflict-free
    int b = blockIdx.y, t = threadIdx.x;
    int tx = t & 31, ty = t >> 5;           // ty in [0,16)
    int p0 = blockIdx.x * 32;
    int p = p0 + tx;
    sFP[t] = FP[b * Cch + t];
    sBP[t] = BP[b * Cch + t];
    __syncthreads();
    float nf = sqrtf(block_sum512(sFP[t] * sFP[t], s8));
    float nb = sqrtf(block_sum512(sBP[t] * sBP[t], s8));
    const float* q = fq + (size_t)b * Cch * Npx + p;
    float df = 0.f, db = 0.f, qq = 0.f;
    int c0 = ty * 32;
    #pragma unroll 4
    for (int c = 0; c < 32; c += 2) {
        float v0 = q[(size_t)(c0 + c) * Npx];
        float v1 = q[(size_t)(c0 + c + 1) * Npx];
        df += v0 * sFP[c0 + c] + v1 * sFP[c0 + c + 1];
        db += v0 * sBP[c0 + c] + v1 * sBP[c0 + c + 1];
        qq += v0 * v0 + v1 * v1;
        unsigned pk = (unsigned)f2bf(v0) | ((unsigned)f2bf(v1) << 16);
        *(unsigned*)&S[tx][c0 + c] = pk;
    }
    rdf[ty][tx] = df; rdb[ty][tx] = db; rqq[ty][tx] = qq;
    __syncthreads();
    for (int s = 8; s > 0; s >>= 1) {
        if (ty < s) {
            rdf[ty][tx] += rdf[ty + s][tx];
            rdb[ty][tx] += rdb[ty + s][tx];
            rqq[ty][tx] += rqq[ty + s][tx];
        }
        __syncthreads();
    }
    if (ty == 0) {
        float nq = sqrtf(rqq[0][tx]);
        float simf = 10.f * rdf[0][tx] / fmaxf(nq * nf, 1e-8f);
        float simb = 10.f * rdb[0][tx] / fmaxf(nq * nb, 1e-8f);
        dsim[b * Npx + p] = simf - simb;
        invn[b * Npx + p] = 1.f / nq;
    }
    // write Ft rows (coalesced dword stores, conflict-free LDS dword reads)
    int w = t >> 6, lane = t & 63;           // 8 waves
    unsigned short* FtB = Ft + (size_t)b * Npx * Cch;
    for (int pr = w; pr < 32; pr += 8) {
        unsigned* dst = (unsigned*)(FtB + (size_t)(p0 + pr) * Cch);
        #pragma unroll
        for (int it = 0; it < 4; it++) {
            int d = it * 64 + lane;
            dst[d] = *(const unsigned*)&S[pr][d * 2];
        }
    }
}

// ---------------- 3: select + compact + prototypes + FP1/nf -------------------
// grid (2, Bsz), block 1024 (16 waves). x=0: fg, x=1: bg
__global__ void __launch_bounds__(1024) k_selcompact(const float* __restrict__ dsim,
                        const float* __restrict__ invn,
                        const unsigned short* __restrict__ Ft,
                        const float* __restrict__ FP,
                        int* __restrict__ nsf, int* __restrict__ nsb,
                        int* __restrict__ jf, int* __restrict__ jb,
                        float* __restrict__ ivg,
                        float* __restrict__ fgp, float* __restrict__ bgp,
                        float* __restrict__ FP1, float* __restrict__ nfv) {
    __shared__ int wsum[16];
    __shared__ int sns;
    __shared__ float sProto[16][512];       // 32 KB
    __shared__ float s16f[16];
    int b = blockIdx.y, t = threadIdx.x;
    int lane = t & 63, w = t >> 6;
    bool isf = (blockIdx.x == 0);
    float d = dsim[b * Npx + t];
    float key = isf ? d : -d;
    float thres = isf ? 0.8472979f : 0.4054651f;   // ln(0.7/0.3), ln(0.6/0.4)
    int flag = (key > thres) ? 1 : 0;
    int x = flag;
    #pragma unroll
    for (int o = 1; o < 64; o <<= 1) {
        int y = __shfl_up(x, o);
        if (lane >= o) x += y;
    }
    if (lane == 63) wsum[w] = x;
    __syncthreads();
    int base = 0, total = 0;
    #pragma unroll
    for (int k = 0; k < 16; k++) {
        int s = wsum[k];
        if (k < w) base += s;
        total += s;
    }
    int* jdst = (isf ? jf : jb) + b * Npx;
    if (total == 0) {
        // cold path: top-12 fallback (lower index wins ties)
        __shared__ int   sc[Npx];
        __shared__ float v[Npx];
        __shared__ float rv[Npx];
        __shared__ int   ri[Npx];
        v[t] = key; flag = 0;
        __syncthreads();
        for (int k = 0; k < TOPK; k++) {
            rv[t] = v[t]; ri[t] = t;
            __syncthreads();
            for (int s = 512; s > 0; s >>= 1) {
                if (t < s) {
                    float a = rv[t], bb = rv[t + s];
                    int ia = ri[t], ib = ri[t + s];
                    if (bb > a || (bb == a && ib < ia)) { rv[t] = bb; ri[t] = ib; }
                }
                __syncthreads();
            }
            int win = ri[0];
            if (t == win) { flag = 1; v[t] = -INFINITY; }
            __syncthreads();
        }
        sc[t] = flag;
        __syncthreads();
        for (int off = 1; off < 1024; off <<= 1) {
            int xx = (t >= off) ? sc[t - off] : 0;
            __syncthreads();
            sc[t] += xx;
            __syncthreads();
        }
        if (flag) {
            int pos = sc[t] - 1;
            jdst[pos] = t;
            if (!isf) ivg[b * Npx + pos] = invn[b * Npx + t];
        }
        if (t == 1023) sns = sc[1023];
    } else {
        if (flag) {
            int pos = base + x - 1;
            jdst[pos] = t;
            if (!isf) ivg[b * Npx + pos] = invn[b * Npx + t];
        }
        if (t == 0) sns = total;
    }
    __syncthreads();                         // jdst writes + sns visible to block
    int ns = sns;
    if (t == 0) (isf ? nsf : nsb)[b] = ns;
    // ---- prototype: mean of selected Ft rows (coalesced 1KB row reads) ----
    const unsigned short* FtB = Ft + (size_t)b * Npx * Cch;
    float facc[8] = {0.f, 0.f, 0.f, 0.f, 0.f, 0.f, 0.f, 0.f};
    int k = w;
    int row = (k < ns) ? jdst[k] : 0;
    while (k < ns) {
        int kn = k + 16;
        int rown = (kn < ns) ? jdst[kn] : 0;   // prefetch index
        bf16x8 vv = *(const bf16x8*)&FtB[(size_t)row * Cch + lane * 8];
        #pragma unroll
        for (int e = 0; e < 8; e++) facc[e] += bf2f((unsigned short)vv[e]);
        k = kn; row = rown;
    }
    #pragma unroll
    for (int e = 0; e < 8; e++) sProto[w][lane * 8 + e] = facc[e];
    __syncthreads();
    float fp1 = 0.f;
    if (t < 512) {
        float s = 0.f;
        #pragma unroll
        for (int q = 0; q < 16; q++) s += sProto[q][t];
        float pv = s / (float)ns;
        (isf ? fgp : bgp)[b * Cch + t] = pv;
        if (isf) {
            fp1 = 0.5f * FP[b * Cch + t] + 0.5f * pv;
            FP1[b * Cch + t] = fp1;
        }
    }
    if (isf) {
        // ||FP1|| for the final fg similarity
        float v2 = warp_sum64(fp1 * fp1);
        if (lane == 0) s16f[w] = v2;
        __syncthreads();
        if (t == 0) {
            float nn = 0.f;
            #pragma unroll
            for (int q = 0; q < 16; q++) nn += s16f[q];
            nfv[b] = sqrtf(nn);
        }
    }
}

// ---------------- 4: FUSED gram + softmax + PV + finalize (compacted-j) -------
// grid 256 (1D, batch->XCD swizzle), block 512 (8 waves), ~149 KB LDS.
// R13: phase 2 inverted to outer-jt -- V-transpose built ONCE per j-tile at
// full 512-c width into Vt (LDS union with phase-1's Afull/Bt2), then 16 MFMAs
// per barrier-pair accumulating accp[4][2] across tiles. Barriers 48 -> ~2T.
// Epilogue once; qv re-read from global (L2-hot); nq taken from f32 invn
// (exact reference normalization) so sqq is dropped.
__global__ void __launch_bounds__(512) k_fused(
        const unsigned short* __restrict__ Ft,
        const int* __restrict__ jb, const int* __restrict__ nsb,
        const float* __restrict__ invn, const float* __restrict__ ivg,
        const float* __restrict__ bgp, const float* __restrict__ FP1,
        const float* __restrict__ nfv, float* __restrict__ out) {
    __shared__ unsigned short U[36864];         // 73.7 KB union:
                                                //  phase1: Afull[32][520] @0 + Bt2[2][64][136] @16640
                                                //  phase2: Vt[512][72] @0
    __shared__ unsigned short sP[32][1032];     // attention rows (66 KB)
    __shared__ int   sji[1024];
    __shared__ float sfj[1024];
    __shared__ float sfp1full[Cch], sbgfull[Cch];
    __shared__ float sfi[32], sden[32];
    __shared__ float spart[32][3];

    unsigned short (*Afull)[520] = (unsigned short(*)[520])U;
    unsigned short (*Bt2)[64][136] = (unsigned short(*)[64][136])(U + 16640);
    unsigned short (*Vt)[72] = (unsigned short(*)[72])U;

    int bid = blockIdx.x;
    int b = bid & 7;                       // batch -> XCD (round-robin heuristic)
    int i0 = (bid >> 3) * 32;
    int tid = threadIdx.x;
    int l = tid & 63, w = tid >> 6;
    int ml = l & 15, quad = l >> 4;
    int ns = nsb[b];
    int K64 = ((((ns + 31) & ~31) + 63) & ~63);
    int T = K64 >> 6;

    const unsigned short* FtB = Ft + (size_t)b * Npx * Cch;

    // ---- stage A (q rows, full K) + tables + full FP1/bgp preload ----
    #pragma unroll
    for (int s = 0; s < 4; s++) {
        int idx = tid + s * 512;
        int row = idx >> 6, kc8 = (idx & 63) * 8;
        *(uint4*)&Afull[row][kc8] = *(const uint4*)(FtB + (size_t)(i0 + row) * Cch + kc8);
    }
    for (int j = tid; j < K64; j += 512) {
        sji[j] = (j < ns) ? jb[b * Npx + j] : jb[b * Npx];
        sfj[j] = (j < ns) ? ivg[b * Npx + j] : 0.f;
    }
    sfp1full[tid] = FP1[b * Cch + tid];
    sbgfull[tid]  = 0.3f * bgp[b * Cch + tid];
    if (tid < 32) sfi[tid] = 2.f * invn[b * Npx + i0 + tid];
    __syncthreads();

    // ---- phase 1: gram rows -> sP = exp(sim) (bf16); dbuf Bt, 1 bar/k-chunk --
    int ig = w & 1, jg = w >> 1;            // 8 waves tile 32i x 64j
    int grow = tid >> 4, gk8 = (tid & 15) * 8;  // staging: rows grow & grow+32
    for (int j0 = 0; j0 < K64; j0 += 64) {
        const unsigned short* pb0 = FtB + (size_t)sji[j0 + grow] * Cch + gk8;
        const unsigned short* pb1 = FtB + (size_t)sji[j0 + 32 + grow] * Cch + gk8;
        uint4 v0 = *(const uint4*)pb0;
        uint4 v1 = *(const uint4*)pb1;
        f32x4 acc = {};
        #pragma unroll
        for (int kt = 0; kt < 4; kt++) {    // Cch/128 chunks
            int buf = kt & 1;
            *(uint4*)&Bt2[buf][grow][gk8] = v0;
            *(uint4*)&Bt2[buf][32 + grow][gk8] = v1;
            int kn = (kt + 1) * 128;
            if (kn < Cch) {                 // prefetch next chunk (in flight over mfma)
                v0 = *(const uint4*)(pb0 + kn);
                v1 = *(const uint4*)(pb1 + kn);
            }
            __syncthreads();                // scatter(buf) visible; readers of buf
                                            // from kt-2 finished before bar(kt-1)
            int k0 = kt * 128;
            #pragma unroll
            for (int h = 0; h < 4; h++) {
                bf16x8 af = *(const bf16x8*)&Afull[ig * 16 + ml][k0 + h * 32 + quad * 8];
                bf16x8 bf = *(const bf16x8*)&Bt2[buf][jg * 16 + ml][h * 32 + quad * 8];
                acc = __builtin_amdgcn_mfma_f32_16x16x32_bf16(af, bf, acc, 0, 0, 0);
            }
        }
        #pragma unroll
        for (int r = 0; r < 4; r++) {
            int il = ig * 16 + quad * 4 + r;
            int jl = jg * 16 + ml;
            float e = (j0 + jl < ns) ? __expf(acc[r] * sfi[il] * sfj[j0 + jl]) : 0.f;
            sP[il][j0 + jl] = f2bf(e);
        }
    }
    __syncthreads();

    // ---- row denominators from sP + zero partial sums ----
    {
        int i = tid >> 4, jj16 = tid & 15;
        float s = 0.f;
        for (int j = jj16; j < K64; j += 16) s += bf2f(sP[i][j]);
        #pragma unroll
        for (int m = 1; m < 16; m <<= 1) s += __shfl_xor(s, m);
        if (jj16 == 0) sden[i] = s;
    }
    if (tid < 96) ((float*)spart)[tid] = 0.f;
    __syncthreads();                        // also: last use of Afull/Bt2 done

    // ---- phase 2: outer-jt PV; Vt built once per tile at full c width ----
    int jp = tid & 31, cgg = tid >> 5;      // scatter: j-pair jp, 32-c group cgg
    f32x4 accp[4][2] = {};
    const unsigned short* rA = FtB + (size_t)sji[2 * jp] * Cch + cgg * 32;
    const unsigned short* rB = FtB + (size_t)sji[2 * jp + 1] * Cch + cgg * 32;
    uint4 a0 = *(const uint4*)rA, a1 = *(const uint4*)(rA + 8);
    uint4 a2 = *(const uint4*)(rA + 16), a3 = *(const uint4*)(rA + 24);
    uint4 b0 = *(const uint4*)rB, b1 = *(const uint4*)(rB + 8);
    uint4 b2 = *(const uint4*)(rB + 16), b3 = *(const uint4*)(rB + 24);
    for (int jt = 0; jt < T; jt++) {
        {   // scatter: Vt[c][j] <- rows (2jp, 2jp+1), u32-packed j-pairs
            unsigned ad[16] = {a0.x, a0.y, a0.z, a0.w, a1.x, a1.y, a1.z, a1.w,
                               a2.x, a2.y, a2.z, a2.w, a3.x, a3.y, a3.z, a3.w};
            unsigned bd[16] = {b0.x, b0.y, b0.z, b0.w, b1.x, b1.y, b1.z, b1.w,
                               b2.x, b2.y, b2.z, b2.w, b3.x, b3.y, b3.z, b3.w};
            #pragma unroll
            for (int d = 0; d < 16; d++) {
                int c = cgg * 32 + 2 * d;
                *(unsigned*)&Vt[c][2 * jp]     = (ad[d] & 0xFFFFu) | (bd[d] << 16);
                *(unsigned*)&Vt[c + 1][2 * jp] = (ad[d] >> 16) | (bd[d] & 0xFFFF0000u);
            }
        }
        if (jt + 1 < T) {                   // prefetch next tile's rows
            rA = FtB + (size_t)sji[(jt + 1) * 64 + 2 * jp] * Cch + cgg * 32;
            rB = FtB + (size_t)sji[(jt + 1) * 64 + 2 * jp + 1] * Cch + cgg * 32;
            a0 = *(const uint4*)rA; a1 = *(const uint4*)(rA + 8);
            a2 = *(const uint4*)(rA + 16); a3 = *(const uint4*)(rA + 24);
            b0 = *(const uint4*)rB; b1 = *(const uint4*)(rB + 8);
            b2 = *(const uint4*)(rB + 16); b3 = *(const uint4*)(rB + 24);
        }
        __syncthreads();                    // Vt ready
        int j0 = jt * 64;
        #pragma unroll
        for (int iff = 0; iff < 2; iff++) {
            bf16x8 p0 = *(const bf16x8*)&sP[iff * 16 + ml][j0 + quad * 8];
            bf16x8 p1 = *(const bf16x8*)&sP[iff * 16 + ml][j0 + 32 + quad * 8];
            #pragma unroll
            for (int cf = 0; cf < 4; cf++) {
                bf16x8 v0 = *(const bf16x8*)&Vt[w * 64 + cf * 16 + ml][quad * 8];
                bf16x8 v1 = *(const bf16x8*)&Vt[w * 64 + cf * 16 + ml][32 + quad * 8];
                accp[cf][iff] = __builtin_amdgcn_mfma_f32_16x16x32_bf16(v0, p0, accp[cf][iff], 0, 0, 0);
                accp[cf][iff] = __builtin_amdgcn_mfma_f32_16x16x32_bf16(v1, p1, accp[cf][iff], 0, 0, 0);
            }
        }
        __syncthreads();                    // Vt consumed; next scatter safe
    }

    // ---- epilogue: per-thread similarity partials (runs once) ----
    float sdb[2] = {0.f, 0.f}, snb[2] = {0.f, 0.f}, sdf[2] = {0.f, 0.f};
    #pragma unroll
    for (int iff = 0; iff < 2; iff++) {
        int icol = iff * 16 + ml;
        float rdi = 1.f / sden[icol];
        #pragma unroll
        for (int cf = 0; cf < 4; cf++) {
            int clb = w * 64 + cf * 16 + quad * 4;
            const unsigned* qp = (const unsigned*)(FtB + (size_t)(i0 + icol) * Cch + clb);
            unsigned q01 = qp[0], q23 = qp[1];
            float qv[4] = { bf2f((unsigned short)(q01 & 0xFFFFu)),
                            bf2f((unsigned short)(q01 >> 16)),
                            bf2f((unsigned short)(q23 & 0xFFFFu)),
                            bf2f((unsigned short)(q23 >> 16)) };
            #pragma unroll
            for (int r = 0; r < 4; r++) {
                int cl = clb + r;
                float loc = accp[cf][iff][r] * rdi;
                float bp1 = sbgfull[cl] + 0.7f * loc;
                sdb[iff] += qv[r] * bp1;
                snb[iff] += bp1 * bp1;
                sdf[iff] += qv[r] * sfp1full[cl];
            }
        }
    }
    #pragma unroll
    for (int iff = 0; iff < 2; iff++) {
        float a = sdb[iff], bq = snb[iff], c = sdf[iff];
        a += __shfl_xor(a, 16);  a += __shfl_xor(a, 32);
        bq += __shfl_xor(bq, 16); bq += __shfl_xor(bq, 32);
        c += __shfl_xor(c, 16);  c += __shfl_xor(c, 32);
        if (quad == 0) {
            int icol = iff * 16 + ml;
            atomicAdd(&spart[icol][0], a);
            atomicAdd(&spart[icol][1], bq);
            atomicAdd(&spart[icol][2], c);
        }
    }
    __syncthreads();
    if (tid < 32) {
        float db = spart[tid][0], nb = spart[tid][1], df = spart[tid][2];
        float nq = 2.f / sfi[tid];          // = 1/invn (f32-exact reference norm)
        float sb2 = 10.f * db / fmaxf(nq * sqrtf(nb), 1e-8f);
        float sf2 = 10.f * df / fmaxf(nq * nfv[b], 1e-8f);
        out[((size_t)b * 2) * Npx + i0 + tid] = sb2;
        out[((size_t)b * 2 + 1) * Npx + i0 + tid] = sf2;
    }
}

extern "C" void kernel_launch(void* const* d_in, const int* in_sizes, int n_in,
                              void* d_out, int out_size, void* d_ws, size_t ws_size,
                              hipStream_t stream) {
    const float* fq = (const float*)d_in[0];
    const float* sf = (const float*)d_in[1];
    const int* mask = (const int*)d_in[2];
    float* out = (float*)d_out;

    float* ws = (float*)d_ws;
    float* FP    = ws;                        // B*C
    float* BP    = FP + Bsz * Cch;
    float* fgp   = BP + Bsz * Cch;
    float* bgp   = fgp + Bsz * Cch;
    float* FP1   = bgp + Bsz * Cch;           // B*C
    float* nfv   = FP1 + Bsz * Cch;           // 8
    float* dsim  = nfv + 8;                   // B*N
    float* invn  = dsim + BN;
    float* ivg   = invn + BN;
    int*   nsf   = (int*)(ivg + BN);          // 8
    int*   nsb   = nsf + 8;                   // 8
    int*   jf    = nsb + 8;                   // B*N
    int*   jb    = jf + BN;                   // B*N
    unsigned short* Ft = (unsigned short*)(jb + BN);                     // 8 MB [i][c]

    k_pool<<<dim3(Cch, Bsz), 256, 0, stream>>>(sf, mask, FP, BP);
    k_predcast<<<dim3(Npx / 32, Bsz), 512, 0, stream>>>(fq, FP, BP, dsim, invn, Ft);
    k_selcompact<<<dim3(2, Bsz), 1024, 0, stream>>>(dsim, invn, Ft, FP, nsf, nsb, jf, jb, ivg, fgp, bgp, FP1, nfv);
    k_fused<<<dim3(256), 512, 0, stream>>>(Ft, jb, nsb, invn, ivg, bgp, FP1, nfv, out);
}

// Round 15
// 123.377 us; speedup vs baseline: 1.4780x; 1.0140x over previous
//
#include <hip/hip_runtime.h>
#include <math.h>

#define Bsz 8
#define Cch 512
#define Npx 1024
#define TOPK 12
#define BN (Bsz * Npx)

typedef __attribute__((ext_vector_type(8))) short bf16x8;
typedef __attribute__((ext_vector_type(4))) float f32x4;

__device__ __forceinline__ unsigned short f2bf(float x) {
    unsigned u = __float_as_uint(x);
    u += 0x7FFF + ((u >> 16) & 1);
    return (unsigned short)(u >> 16);
}
__device__ __forceinline__ float bf2f(unsigned short h) {
    return __uint_as_float(((unsigned)h) << 16);
}

// ---------------- reduction helpers ----------------
__device__ __forceinline__ float warp_sum64(float v) {
    for (int o = 32; o > 0; o >>= 1) v += __shfl_down(v, o);
    return v;
}
__device__ __forceinline__ float block_sum512(float v, float* s8) {
    v = warp_sum64(v);
    int lane = threadIdx.x & 63, w = threadIdx.x >> 6;
    __syncthreads();
    if (lane == 0) s8[w] = v;
    __syncthreads();
    float r = 0.f;
    #pragma unroll
    for (int k = 0; k < 8; k++) r += s8[k];
    return r;
}

// ---------------- 1: masked average pool (float4, single-barrier) -------------
// grid (Cch, Bsz), block 256
__global__ void k_pool(const float* __restrict__ sf, const int* __restrict__ mask,
                       float* __restrict__ FPo, float* __restrict__ BPo) {
    __shared__ float s4a[4], s4b[4], s4c[4];
    int c = blockIdx.x, b = blockIdx.y, t = threadIdx.x;
    const float4* f4 = (const float4*)(sf + ((size_t)b * Cch + c) * Npx);
    const int4* m4 = (const int4*)(mask + (size_t)b * Npx);
    float4 v = f4[t];
    int4 m = m4[t];
    float sumf = (m.x == 1 ? v.x : 0.f) + (m.y == 1 ? v.y : 0.f)
               + (m.z == 1 ? v.z : 0.f) + (m.w == 1 ? v.w : 0.f);
    float tot = v.x + v.y + v.z + v.w;
    float cf = (float)((m.x == 1) + (m.y == 1) + (m.z == 1) + (m.w == 1));
    sumf = warp_sum64(sumf);
    tot  = warp_sum64(tot);
    cf   = warp_sum64(cf);
    int lane = t & 63, w = t >> 6;
    if (lane == 0) { s4a[w] = sumf; s4b[w] = tot; s4c[w] = cf; }
    __syncthreads();
    if (t == 0) {
        float sA = s4a[0] + s4a[1] + s4a[2] + s4a[3];
        float sB = s4b[0] + s4b[1] + s4b[2] + s4b[3];
        float sC = s4c[0] + s4c[1] + s4c[2] + s4c[3];
        FPo[b * Cch + c] = sA / (sC + 1e-5f);
        BPo[b * Cch + c] = (sB - sA) / ((1024.f - sC) + 1e-5f);
    }
}

// ---------------- 2: pred logit + bf16 cast (block 512: 16 thr/pixel) ---------
// grid (Npx/32, Bsz), block 512.
__global__ void __launch_bounds__(512) k_predcast(const float* __restrict__ fq,
                       const float* __restrict__ FP, const float* __restrict__ BP,
                       float* __restrict__ dsim, float* __restrict__ invn,
                       unsigned short* __restrict__ Ft) {
    __shared__ float sFP[Cch], sBP[Cch], s8[8];
    __shared__ float rdf[16][32], rdb[16][32], rqq[16][32];
    __shared__ unsigned short S[32][522];   // odd dword stride -> conflict-free
    int b = blockIdx.y, t = threadIdx.x;
    int tx = t & 31, ty = t >> 5;           // ty in [0,16)
    int p0 = blockIdx.x * 32;
    int p = p0 + tx;
    sFP[t] = FP[b * Cch + t];
    sBP[t] = BP[b * Cch + t];
    __syncthreads();
    float nf = sqrtf(block_sum512(sFP[t] * sFP[t], s8));
    float nb = sqrtf(block_sum512(sBP[t] * sBP[t], s8));
    const float* q = fq + (size_t)b * Cch * Npx + p;
    float df = 0.f, db = 0.f, qq = 0.f;
    int c0 = ty * 32;
    #pragma unroll 4
    for (int c = 0; c < 32; c += 2) {
        float v0 = q[(size_t)(c0 + c) * Npx];
        float v1 = q[(size_t)(c0 + c + 1) * Npx];
        df += v0 * sFP[c0 + c] + v1 * sFP[c0 + c + 1];
        db += v0 * sBP[c0 + c] + v1 * sBP[c0 + c + 1];
        qq += v0 * v0 + v1 * v1;
        unsigned pk = (unsigned)f2bf(v0) | ((unsigned)f2bf(v1) << 16);
        *(unsigned*)&S[tx][c0 + c] = pk;
    }
    rdf[ty][tx] = df; rdb[ty][tx] = db; rqq[ty][tx] = qq;
    __syncthreads();
    for (int s = 8; s > 0; s >>= 1) {
        if (ty < s) {
            rdf[ty][tx] += rdf[ty + s][tx];
            rdb[ty][tx] += rdb[ty + s][tx];
            rqq[ty][tx] += rqq[ty + s][tx];
        }
        __syncthreads();
    }
    if (ty == 0) {
        float nq = sqrtf(rqq[0][tx]);
        float simf = 10.f * rdf[0][tx] / fmaxf(nq * nf, 1e-8f);
        float simb = 10.f * rdb[0][tx] / fmaxf(nq * nb, 1e-8f);
        dsim[b * Npx + p] = simf - simb;
        invn[b * Npx + p] = 1.f / nq;
    }
    // write Ft rows (coalesced dword stores, conflict-free LDS dword reads)
    int w = t >> 6, lane = t & 63;           // 8 waves
    unsigned short* FtB = Ft + (size_t)b * Npx * Cch;
    for (int pr = w; pr < 32; pr += 8) {
        unsigned* dst = (unsigned*)(FtB + (size_t)(p0 + pr) * Cch);
        #pragma unroll
        for (int it = 0; it < 4; it++) {
            int d = it * 64 + lane;
            dst[d] = *(const unsigned*)&S[pr][d * 2];
        }
    }
}

// ---------------- 3: select + compact + prototypes + FP1/nf -------------------
// grid (2, Bsz), block 1024 (16 waves). x=0: fg, x=1: bg
__global__ void __launch_bounds__(1024) k_selcompact(const float* __restrict__ dsim,
                        const float* __restrict__ invn,
                        const unsigned short* __restrict__ Ft,
                        const float* __restrict__ FP,
                        int* __restrict__ nsf, int* __restrict__ nsb,
                        int* __restrict__ jf, int* __restrict__ jb,
                        float* __restrict__ ivg,
                        float* __restrict__ fgp, float* __restrict__ bgp,
                        float* __restrict__ FP1, float* __restrict__ nfv) {
    __shared__ int wsum[16];
    __shared__ int sns;
    __shared__ float sProto[16][512];       // 32 KB
    __shared__ float s16f[16];
    int b = blockIdx.y, t = threadIdx.x;
    int lane = t & 63, w = t >> 6;
    bool isf = (blockIdx.x == 0);
    float d = dsim[b * Npx + t];
    float key = isf ? d : -d;
    float thres = isf ? 0.8472979f : 0.4054651f;   // ln(0.7/0.3), ln(0.6/0.4)
    int flag = (key > thres) ? 1 : 0;
    int x = flag;
    #pragma unroll
    for (int o = 1; o < 64; o <<= 1) {
        int y = __shfl_up(x, o);
        if (lane >= o) x += y;
    }
    if (lane == 63) wsum[w] = x;
    __syncthreads();
    int base = 0, total = 0;
    #pragma unroll
    for (int k = 0; k < 16; k++) {
        int s = wsum[k];
        if (k < w) base += s;
        total += s;
    }
    int* jdst = (isf ? jf : jb) + b * Npx;
    if (total == 0) {
        // cold path: top-12 fallback (lower index wins ties)
        __shared__ int   sc[Npx];
        __shared__ float v[Npx];
        __shared__ float rv[Npx];
        __shared__ int   ri[Npx];
        v[t] = key; flag = 0;
        __syncthreads();
        for (int k = 0; k < TOPK; k++) {
            rv[t] = v[t]; ri[t] = t;
            __syncthreads();
            for (int s = 512; s > 0; s >>= 1) {
                if (t < s) {
                    float a = rv[t], bb = rv[t + s];
                    int ia = ri[t], ib = ri[t + s];
                    if (bb > a || (bb == a && ib < ia)) { rv[t] = bb; ri[t] = ib; }
                }
                __syncthreads();
            }
            int win = ri[0];
            if (t == win) { flag = 1; v[t] = -INFINITY; }
            __syncthreads();
        }
        sc[t] = flag;
        __syncthreads();
        for (int off = 1; off < 1024; off <<= 1) {
            int xx = (t >= off) ? sc[t - off] : 0;
            __syncthreads();
            sc[t] += xx;
            __syncthreads();
        }
        if (flag) {
            int pos = sc[t] - 1;
            jdst[pos] = t;
            if (!isf) ivg[b * Npx + pos] = invn[b * Npx + t];
        }
        if (t == 1023) sns = sc[1023];
    } else {
        if (flag) {
            int pos = base + x - 1;
            jdst[pos] = t;
            if (!isf) ivg[b * Npx + pos] = invn[b * Npx + t];
        }
        if (t == 0) sns = total;
    }
    __syncthreads();                         // jdst writes + sns visible to block
    int ns = sns;
    if (t == 0) (isf ? nsf : nsb)[b] = ns;
    // ---- prototype: mean of selected Ft rows (coalesced 1KB row reads) ----
    const unsigned short* FtB = Ft + (size_t)b * Npx * Cch;
    float facc[8] = {0.f, 0.f, 0.f, 0.f, 0.f, 0.f, 0.f, 0.f};
    int k = w;
    int row = (k < ns) ? jdst[k] : 0;
    while (k < ns) {
        int kn = k + 16;
        int rown = (kn < ns) ? jdst[kn] : 0;   // prefetch index
        bf16x8 vv = *(const bf16x8*)&FtB[(size_t)row * Cch + lane * 8];
        #pragma unroll
        for (int e = 0; e < 8; e++) facc[e] += bf2f((unsigned short)vv[e]);
        k = kn; row = rown;
    }
    #pragma unroll
    for (int e = 0; e < 8; e++) sProto[w][lane * 8 + e] = facc[e];
    __syncthreads();
    float fp1 = 0.f;
    if (t < 512) {
        float s = 0.f;
        #pragma unroll
        for (int q = 0; q < 16; q++) s += sProto[q][t];
        float pv = s / (float)ns;
        (isf ? fgp : bgp)[b * Cch + t] = pv;
        if (isf) {
            fp1 = 0.5f * FP[b * Cch + t] + 0.5f * pv;
            FP1[b * Cch + t] = fp1;
        }
    }
    if (isf) {
        // ||FP1|| for the final fg similarity
        float v2 = warp_sum64(fp1 * fp1);
        if (lane == 0) s16f[w] = v2;
        __syncthreads();
        if (t == 0) {
            float nn = 0.f;
            #pragma unroll
            for (int q = 0; q < 16; q++) nn += s16f[q];
            nfv[b] = sqrtf(nn);
        }
    }
}

// ---------------- 4: FUSED gram + softmax + PV + finalize (compacted-j) -------
// grid 256 (1D, batch->XCD swizzle), block 512 (8 waves), ~152 KB LDS.
// R15: A-operand held ENTIRELY in registers (16 bf16x8 fragments, invariant
// across the j0 loop) -- stage-A LDS buffer and its per-interval ds_reads
// deleted; phase-1 MFMAs depend only on the Bt2 scatter. Phase 2 unchanged
// from R13 (outer-jt, Vt built once per tile at full c width).
__global__ void __launch_bounds__(512) k_fused(
        const unsigned short* __restrict__ Ft,
        const int* __restrict__ jb, const int* __restrict__ nsb,
        const float* __restrict__ invn, const float* __restrict__ ivg,
        const float* __restrict__ bgp, const float* __restrict__ FP1,
        const float* __restrict__ nfv, float* __restrict__ out) {
    __shared__ unsigned short U[36864];         // 73.7 KB union:
                                                //  phase1: Bt2[2][64][136] @0
                                                //  phase2: Vt[512][72] @0
    __shared__ unsigned short sP[32][1032];     // attention rows (66 KB)
    __shared__ int   sji[1024];
    __shared__ float sfj[1024];
    __shared__ float sfp1full[Cch], sbgfull[Cch];
    __shared__ float sfi[32], sden[32];
    __shared__ float spart[32][3];

    unsigned short (*Bt2)[64][136] = (unsigned short(*)[64][136])U;
    unsigned short (*Vt)[72] = (unsigned short(*)[72])U;

    int bid = blockIdx.x;
    int b = bid & 7;                       // batch -> XCD (round-robin heuristic)
    int i0 = (bid >> 3) * 32;
    int tid = threadIdx.x;
    int l = tid & 63, w = tid >> 6;
    int ml = l & 15, quad = l >> 4;
    int ns = nsb[b];
    int K64 = ((((ns + 31) & ~31) + 63) & ~63);
    int T = K64 >> 6;

    const unsigned short* FtB = Ft + (size_t)b * Npx * Cch;
    int ig = w & 1, jg = w >> 1;            // 8 waves tile 32i x 64j (phase 1)

    // ---- A-fragments in registers (j0-invariant; L2-hot 16B loads) ----
    bf16x8 afr[4][4];
    {
        const unsigned short* aro = FtB + (size_t)(i0 + ig * 16 + ml) * Cch + quad * 8;
        #pragma unroll
        for (int kt = 0; kt < 4; kt++)
            #pragma unroll
            for (int h = 0; h < 4; h++)
                afr[kt][h] = *(const bf16x8*)(aro + kt * 128 + h * 32);
    }

    // ---- tables + full FP1/bgp preload ----
    for (int j = tid; j < K64; j += 512) {
        sji[j] = (j < ns) ? jb[b * Npx + j] : jb[b * Npx];
        sfj[j] = (j < ns) ? ivg[b * Npx + j] : 0.f;
    }
    sfp1full[tid] = FP1[b * Cch + tid];
    sbgfull[tid]  = 0.3f * bgp[b * Cch + tid];
    if (tid < 32) sfi[tid] = 2.f * invn[b * Npx + i0 + tid];
    __syncthreads();

    // ---- phase 1: gram rows -> sP = exp(sim) (bf16); dbuf Bt, 1 bar/k-chunk --
    int grow = tid >> 4, gk8 = (tid & 15) * 8;  // staging: rows grow & grow+32
    for (int j0 = 0; j0 < K64; j0 += 64) {
        const unsigned short* pb0 = FtB + (size_t)sji[j0 + grow] * Cch + gk8;
        const unsigned short* pb1 = FtB + (size_t)sji[j0 + 32 + grow] * Cch + gk8;
        uint4 v0 = *(const uint4*)pb0;
        uint4 v1 = *(const uint4*)pb1;
        f32x4 acc = {};
        #pragma unroll
        for (int kt = 0; kt < 4; kt++) {    // Cch/128 chunks
            int buf = kt & 1;
            *(uint4*)&Bt2[buf][grow][gk8] = v0;
            *(uint4*)&Bt2[buf][32 + grow][gk8] = v1;
            int kn = (kt + 1) * 128;
            if (kn < Cch) {                 // prefetch next chunk (in flight over mfma)
                v0 = *(const uint4*)(pb0 + kn);
                v1 = *(const uint4*)(pb1 + kn);
            }
            __syncthreads();                // scatter(buf) visible; readers of buf
                                            // from kt-2 finished before bar(kt-1)
            #pragma unroll
            for (int h = 0; h < 4; h++) {
                bf16x8 bf = *(const bf16x8*)&Bt2[buf][jg * 16 + ml][h * 32 + quad * 8];
                acc = __builtin_amdgcn_mfma_f32_16x16x32_bf16(afr[kt][h], bf, acc, 0, 0, 0);
            }
        }
        #pragma unroll
        for (int r = 0; r < 4; r++) {
            int il = ig * 16 + quad * 4 + r;
            int jl = jg * 16 + ml;
            float e = (j0 + jl < ns) ? __expf(acc[r] * sfi[il] * sfj[j0 + jl]) : 0.f;
            sP[il][j0 + jl] = f2bf(e);
        }
    }
    __syncthreads();

    // ---- row denominators from sP + zero partial sums ----
    {
        int i = tid >> 4, jj16 = tid & 15;
        float s = 0.f;
        for (int j = jj16; j < K64; j += 16) s += bf2f(sP[i][j]);
        #pragma unroll
        for (int m = 1; m < 16; m <<= 1) s += __shfl_xor(s, m);
        if (jj16 == 0) sden[i] = s;
    }
    if (tid < 96) ((float*)spart)[tid] = 0.f;
    __syncthreads();                        // also: last use of Bt2 done

    // ---- phase 2: outer-jt PV; Vt built once per tile at full c width ----
    int jp = tid & 31, cgg = tid >> 5;      // scatter: j-pair jp, 32-c group cgg
    f32x4 accp[4][2] = {};
    const unsigned short* rA = FtB + (size_t)sji[2 * jp] * Cch + cgg * 32;
    const unsigned short* rB = FtB + (size_t)sji[2 * jp + 1] * Cch + cgg * 32;
    uint4 a0 = *(const uint4*)rA, a1 = *(const uint4*)(rA + 8);
    uint4 a2 = *(const uint4*)(rA + 16), a3 = *(const uint4*)(rA + 24);
    uint4 b0 = *(const uint4*)rB, b1 = *(const uint4*)(rB + 8);
    uint4 b2 = *(const uint4*)(rB + 16), b3 = *(const uint4*)(rB + 24);
    for (int jt = 0; jt < T; jt++) {
        {   // scatter: Vt[c][j] <- rows (2jp, 2jp+1), u32-packed j-pairs
            unsigned ad[16] = {a0.x, a0.y, a0.z, a0.w, a1.x, a1.y, a1.z, a1.w,
                               a2.x, a2.y, a2.z, a2.w, a3.x, a3.y, a3.z, a3.w};
            unsigned bd[16] = {b0.x, b0.y, b0.z, b0.w, b1.x, b1.y, b1.z, b1.w,
                               b2.x, b2.y, b2.z, b2.w, b3.x, b3.y, b3.z, b3.w};
            #pragma unroll
            for (int d = 0; d < 16; d++) {
                int c = cgg * 32 + 2 * d;
                *(unsigned*)&Vt[c][2 * jp]     = (ad[d] & 0xFFFFu) | (bd[d] << 16);
                *(unsigned*)&Vt[c + 1][2 * jp] = (ad[d] >> 16) | (bd[d] & 0xFFFF0000u);
            }
        }
        if (jt + 1 < T) {                   // prefetch next tile's rows
            rA = FtB + (size_t)sji[(jt + 1) * 64 + 2 * jp] * Cch + cgg * 32;
            rB = FtB + (size_t)sji[(jt + 1) * 64 + 2 * jp + 1] * Cch + cgg * 32;
            a0 = *(const uint4*)rA; a1 = *(const uint4*)(rA + 8);
            a2 = *(const uint4*)(rA + 16); a3 = *(const uint4*)(rA + 24);
            b0 = *(const uint4*)rB; b1 = *(const uint4*)(rB + 8);
            b2 = *(const uint4*)(rB + 16); b3 = *(const uint4*)(rB + 24);
        }
        __syncthreads();                    // Vt ready
        int j0 = jt * 64;
        #pragma unroll
        for (int iff = 0; iff < 2; iff++) {
            bf16x8 p0 = *(const bf16x8*)&sP[iff * 16 + ml][j0 + quad * 8];
            bf16x8 p1 = *(const bf16x8*)&sP[iff * 16 + ml][j0 + 32 + quad * 8];
            #pragma unroll
            for (int cf = 0; cf < 4; cf++) {
                bf16x8 v0 = *(const bf16x8*)&Vt[w * 64 + cf * 16 + ml][quad * 8];
                bf16x8 v1 = *(const bf16x8*)&Vt[w * 64 + cf * 16 + ml][32 + quad * 8];
                accp[cf][iff] = __builtin_amdgcn_mfma_f32_16x16x32_bf16(v0, p0, accp[cf][iff], 0, 0, 0);
                accp[cf][iff] = __builtin_amdgcn_mfma_f32_16x16x32_bf16(v1, p1, accp[cf][iff], 0, 0, 0);
            }
        }
        __syncthreads();                    // Vt consumed; next scatter safe
    }

    // ---- epilogue: per-thread similarity partials (runs once) ----
    float sdb[2] = {0.f, 0.f}, snb[2] = {0.f, 0.f}, sdf[2] = {0.f, 0.f};
    #pragma unroll
    for (int iff = 0; iff < 2; iff++) {
        int icol = iff * 16 + ml;
        float rdi = 1.f / sden[icol];
        #pragma unroll
        for (int cf = 0; cf < 4; cf++) {
            int clb = w * 64 + cf * 16 + quad * 4;
            const unsigned* qp = (const unsigned*)(FtB + (size_t)(i0 + icol) * Cch + clb);
            unsigned q01 = qp[0], q23 = qp[1];
            float qv[4] = { bf2f((unsigned short)(q01 & 0xFFFFu)),
                            bf2f((unsigned short)(q01 >> 16)),
                            bf2f((unsigned short)(q23 & 0xFFFFu)),
                            bf2f((unsigned short)(q23 >> 16)) };
            #pragma unroll
            for (int r = 0; r < 4; r++) {
                int cl = clb + r;
                float loc = accp[cf][iff][r] * rdi;
                float bp1 = sbgfull[cl] + 0.7f * loc;
                sdb[iff] += qv[r] * bp1;
                snb[iff] += bp1 * bp1;
                sdf[iff] += qv[r] * sfp1full[cl];
            }
        }
    }
    #pragma unroll
    for (int iff = 0; iff < 2; iff++) {
        float a = sdb[iff], bq = snb[iff], c = sdf[iff];
        a += __shfl_xor(a, 16);  a += __shfl_xor(a, 32);
        bq += __shfl_xor(bq, 16); bq += __shfl_xor(bq, 32);
        c += __shfl_xor(c, 16);  c += __shfl_xor(c, 32);
        if (quad == 0) {
            int icol = iff * 16 + ml;
            atomicAdd(&spart[icol][0], a);
            atomicAdd(&spart[icol][1], bq);
            atomicAdd(&spart[icol][2], c);
        }
    }
    __syncthreads();
    if (tid < 32) {
        float db = spart[tid][0], nb = spart[tid][1], df = spart[tid][2];
        float nq = 2.f / sfi[tid];          // = 1/invn (f32-exact reference norm)
        float sb2 = 10.f * db / fmaxf(nq * sqrtf(nb), 1e-8f);
        float sf2 = 10.f * df / fmaxf(nq * nfv[b], 1e-8f);
        out[((size_t)b * 2) * Npx + i0 + tid] = sb2;
        out[((size_t)b * 2 + 1) * Npx + i0 + tid] = sf2;
    }
}

extern "C" void kernel_launch(void* const* d_in, const int* in_sizes, int n_in,
                              void* d_out, int out_size, void* d_ws, size_t ws_size,
                              hipStream_t stream) {
    const float* fq = (const float*)d_in[0];
    const float* sf = (const float*)d_in[1];
    const int* mask = (const int*)d_in[2];
    float* out = (float*)d_out;

    float* ws = (float*)d_ws;
    float* FP    = ws;                        // B*C
    float* BP    = FP + Bsz * Cch;
    float* fgp   = BP + Bsz * Cch;
    float* bgp   = fgp + Bsz * Cch;
    float* FP1   = bgp + Bsz * Cch;           // B*C
    float* nfv   = FP1 + Bsz * Cch;           // 8
    float* dsim  = nfv + 8;                   // B*N
    float* invn  = dsim + BN;
    float* ivg   = invn + BN;
    int*   nsf   = (int*)(ivg + BN);          // 8
    int*   nsb   = nsf + 8;                   // 8
    int*   jf    = nsb + 8;                   // B*N
    int*   jb    = jf + BN;                   // B*N
    unsigned short* Ft = (unsigned short*)(jb + BN);                     // 8 MB [i][c]

    k_pool<<<dim3(Cch, Bsz), 256, 0, stream>>>(sf, mask, FP, BP);
    k_predcast<<<dim3(Npx / 32, Bsz), 512, 0, stream>>>(fq, FP, BP, dsim, invn, Ft);
    k_selcompact<<<dim3(2, Bsz), 1024, 0, stream>>>(dsim, invn, Ft, FP, nsf, nsb, jf, jb, ivg, fgp, bgp, FP1, nfv);
    k_fused<<<dim3(256), 512, 0, stream>>>(Ft, jb, nsb, invn, ivg, bgp, FP1, nfv, out);
}